// Round 1
// baseline (532.493 us; speedup 1.0000x reference)
//
#include <hip/hip_runtime.h>

#define SEQ 2048
#define HIDDEN 4096
#define NH 32
#define NKV 8
#define HD 128
#define QKV_OUT 6144   // (32 + 2*8) * 128
#define SM_SCALE (1.0f / 128.0f)

typedef __attribute__((ext_vector_type(8))) short bf16x8;
typedef __attribute__((ext_vector_type(4))) float f32x4;

__device__ inline unsigned short f32_bf16(float f) {
  union { float f; unsigned int u; } v; v.f = f;
  unsigned int r = v.u + 0x7FFFu + ((v.u >> 16) & 1u);
  return (unsigned short)(r >> 16);
}

// ---------------- fp32 -> bf16 bulk conversion ----------------
__global__ __launch_bounds__(256) void conv_bf16(const float* __restrict__ in,
                                                 unsigned short* __restrict__ out,
                                                 int n) {
  int i = (blockIdx.x * 256 + threadIdx.x) * 8;
  if (i + 8 > n) return;
  float4 a = *reinterpret_cast<const float4*>(in + i);
  float4 b = *reinterpret_cast<const float4*>(in + i + 4);
  unsigned short t[8];
  t[0] = f32_bf16(a.x); t[1] = f32_bf16(a.y); t[2] = f32_bf16(a.z); t[3] = f32_bf16(a.w);
  t[4] = f32_bf16(b.x); t[5] = f32_bf16(b.y); t[6] = f32_bf16(b.z); t[7] = f32_bf16(b.w);
  *reinterpret_cast<uint4*>(out + i) = *reinterpret_cast<uint4*>(t);
}

// ---------------- RoPE cos/sin tables [SEQ][64] ----------------
__global__ __launch_bounds__(256) void build_tab(float* __restrict__ ct,
                                                 float* __restrict__ st) {
  int idx = blockIdx.x * 256 + threadIdx.x;  // SEQ*64
  int s = idx >> 6, d = idx & 63;
  float inv = powf(1.0e6f, -(float)d * (1.0f / 64.0f));
  float f = (float)s * inv;
  ct[idx] = cosf(f);
  st[idx] = sinf(f);
}

// ---------------- GEMM: C[M,N] = A[M,K] * B[N,K]^T + bias ----------------
// A,B bf16 row-major; C fp32. M,N % 128 == 0, K % 32 == 0. 256 threads.
__global__ __launch_bounds__(256) void gemm_bt(const unsigned short* __restrict__ A,
                                               const unsigned short* __restrict__ B,
                                               const float* __restrict__ bias,
                                               float* __restrict__ C,
                                               int M, int N, int K) {
  __shared__ unsigned short As[128][40];  // +8 pad: <=2-way bank conflicts
  __shared__ unsigned short Bs[128][40];
  const int tid = threadIdx.x;
  const int wave = tid >> 6, lane = tid & 63;
  const int wr = wave >> 1, wc = wave & 1;
  const int lrow = lane & 15, lgrp = lane >> 4;
  const int bm = blockIdx.y * 128, bn = blockIdx.x * 128;
  f32x4 acc[4][4] = {};

  for (int k0 = 0; k0 < K; k0 += 32) {
#pragma unroll
    for (int i = 0; i < 2; ++i) {
      int idx = i * 256 + tid;          // 0..511
      int r = idx >> 2, c = (idx & 3) * 8;
      *reinterpret_cast<uint4*>(&As[r][c]) =
          *reinterpret_cast<const uint4*>(&A[(size_t)(bm + r) * K + k0 + c]);
      *reinterpret_cast<uint4*>(&Bs[r][c]) =
          *reinterpret_cast<const uint4*>(&B[(size_t)(bn + r) * K + k0 + c]);
    }
    __syncthreads();
    bf16x8 a[4], b[4];
#pragma unroll
    for (int m = 0; m < 4; ++m)
      a[m] = *reinterpret_cast<const bf16x8*>(&As[wr * 64 + m * 16 + lrow][lgrp * 8]);
#pragma unroll
    for (int n = 0; n < 4; ++n)
      b[n] = *reinterpret_cast<const bf16x8*>(&Bs[wc * 64 + n * 16 + lrow][lgrp * 8]);
#pragma unroll
    for (int m = 0; m < 4; ++m)
#pragma unroll
      for (int n = 0; n < 4; ++n)
        acc[m][n] = __builtin_amdgcn_mfma_f32_16x16x32_bf16(a[m], b[n], acc[m][n], 0, 0, 0);
    __syncthreads();
  }
#pragma unroll
  for (int m = 0; m < 4; ++m)
#pragma unroll
    for (int n = 0; n < 4; ++n) {
      int col = bn + wc * 64 + n * 16 + lrow;
      float bv = bias[col];
#pragma unroll
      for (int r = 0; r < 4; ++r) {
        int row = bm + wr * 64 + m * 16 + lgrp * 4 + r;
        C[(size_t)row * N + col] = acc[m][n][r] + bv;
      }
    }
}

// ---------------- RoPE + split into Q / K / V^T (bf16) ----------------
// qkv fp32 [SEQ][48*128] viewed as [SEQ][8 groups][6 slots][128].
// slots 0..3 -> Q heads (rope), slot 4 -> K (rope), slot 5 -> V (transposed).
__global__ __launch_bounds__(256) void rope_split(const float* __restrict__ qkv,
                                                  const float* __restrict__ ct,
                                                  const float* __restrict__ st,
                                                  unsigned short* __restrict__ Q,
                                                  unsigned short* __restrict__ Kh,
                                                  unsigned short* __restrict__ Vt) {
  int idx = blockIdx.x * 256 + threadIdx.x;  // SEQ*48*128
  int d = idx & 127;
  int t = idx >> 7;
  int head = t % 48;
  int s = t / 48;
  int gg = head / 6, slot = head - gg * 6;
  const float* base = qkv + (size_t)s * QKV_OUT + gg * 768 + slot * 128;
  float x = base[d];
  if (slot == 5) {
    Vt[((size_t)gg * HD + d) * SEQ + s] = f32_bf16(x);
  } else {
    int dm = d & 63;
    float c = ct[s * 64 + dm], sn = st[s * 64 + dm];
    float rot = (d < 64) ? -base[d + 64] : base[d - 64];
    unsigned short ob = f32_bf16(x * c + rot * sn);
    if (slot < 4)
      Q[((size_t)(gg * 4 + slot) * SEQ + s) * HD + d] = ob;
    else
      Kh[((size_t)gg * SEQ + s) * HD + d] = ob;
  }
}

// ---------------- blocksparse flash attention ----------------
// grid = (NH, SEQ/64). 256 threads = 4 waves, each wave owns 16 q-rows.
// Q [NH][SEQ][HD], Kh [NKV][SEQ][HD], Vt [NKV][HD][SEQ]; ctx bf16 [SEQ][HIDDEN].
__global__ __launch_bounds__(256) void attn(const unsigned short* __restrict__ Q,
                                            const unsigned short* __restrict__ Kh,
                                            const unsigned short* __restrict__ Vt,
                                            unsigned short* __restrict__ ctx) {
  const int h = blockIdx.x, qb = blockIdx.y;
  const int g = h >> 2;
  const int wave = threadIdx.x >> 6, lane = threadIdx.x & 63;
  const int lrow = lane & 15, lgrp = lane >> 4;
  __shared__ unsigned short P[4][16][72];  // per-wave P tile (16 x 64, padded)

  bf16x8 qf[4];
  const unsigned short* qbase = Q + ((size_t)h * SEQ + (size_t)qb * 64 + wave * 16 + lrow) * HD;
#pragma unroll
  for (int kk = 0; kk < 4; ++kk)
    qf[kk] = *reinterpret_cast<const bf16x8*>(qbase + kk * 32 + lgrp * 8);

  f32x4 o[8] = {};
  float mrow[4] = {-1e30f, -1e30f, -1e30f, -1e30f};
  float lsum[4] = {0.f, 0.f, 0.f, 0.f};

  for (int j = 0; j <= qb; ++j) {
    if (!((qb - j) < 16 || ((j + 1) & 7) == 0)) continue;  // blocksparse pattern

    // S = Q * K^T for this 64-col block
    f32x4 s[4] = {};
#pragma unroll
    for (int kk = 0; kk < 4; ++kk) {
#pragma unroll
      for (int n = 0; n < 4; ++n) {
        bf16x8 kf = *reinterpret_cast<const bf16x8*>(
            Kh + ((size_t)g * SEQ + (size_t)j * 64 + n * 16 + lrow) * HD + kk * 32 + lgrp * 8);
        s[n] = __builtin_amdgcn_mfma_f32_16x16x32_bf16(qf[kk], kf, s[n], 0, 0, 0);
      }
    }

    const bool diag = (j == qb);
#pragma unroll
    for (int n = 0; n < 4; ++n)
#pragma unroll
      for (int r = 0; r < 4; ++r) {
        float v = s[n][r] * SM_SCALE;
        if (diag && (n * 16 + lrow) > (wave * 16 + lgrp * 4 + r)) v = -1e30f;
        s[n][r] = v;
      }

    // online softmax, per row r (rows live in 16-lane groups)
#pragma unroll
    for (int r = 0; r < 4; ++r) {
      float v = fmaxf(fmaxf(s[0][r], s[1][r]), fmaxf(s[2][r], s[3][r]));
      v = fmaxf(v, __shfl_xor(v, 1));
      v = fmaxf(v, __shfl_xor(v, 2));
      v = fmaxf(v, __shfl_xor(v, 4));
      v = fmaxf(v, __shfl_xor(v, 8));
      float nm = fmaxf(mrow[r], v);
      float corr = __expf(mrow[r] - nm);
      mrow[r] = nm;
      float ps = 0.f;
#pragma unroll
      for (int n = 0; n < 4; ++n) {
        float p = __expf(s[n][r] - nm);
        s[n][r] = p;
        ps += p;
      }
      ps += __shfl_xor(ps, 1);
      ps += __shfl_xor(ps, 2);
      ps += __shfl_xor(ps, 4);
      ps += __shfl_xor(ps, 8);
      lsum[r] = lsum[r] * corr + ps;
#pragma unroll
      for (int n = 0; n < 8; ++n) o[n][r] *= corr;
    }

    // P (C-layout) -> LDS -> A-fragments (intra-wave, no barrier needed)
#pragma unroll
    for (int n = 0; n < 4; ++n)
#pragma unroll
      for (int r = 0; r < 4; ++r)
        P[wave][lgrp * 4 + r][n * 16 + lrow] = f32_bf16(s[n][r]);
    bf16x8 pa0 = *reinterpret_cast<const bf16x8*>(&P[wave][lrow][lgrp * 8]);
    bf16x8 pa1 = *reinterpret_cast<const bf16x8*>(&P[wave][lrow][32 + lgrp * 8]);

    // O += P * V  (V^T layout makes B-fragments contiguous)
#pragma unroll
    for (int n = 0; n < 8; ++n) {
      const unsigned short* vb = Vt + ((size_t)g * HD + n * 16 + lrow) * SEQ + (size_t)j * 64;
      bf16x8 v0 = *reinterpret_cast<const bf16x8*>(vb + lgrp * 8);
      o[n] = __builtin_amdgcn_mfma_f32_16x16x32_bf16(pa0, v0, o[n], 0, 0, 0);
      bf16x8 v1 = *reinterpret_cast<const bf16x8*>(vb + 32 + lgrp * 8);
      o[n] = __builtin_amdgcn_mfma_f32_16x16x32_bf16(pa1, v1, o[n], 0, 0, 0);
    }
  }

  // normalize + write ctx (bf16) as [SEQ][HIDDEN]
#pragma unroll
  for (int n = 0; n < 8; ++n) {
    int col = h * HD + n * 16 + lrow;
#pragma unroll
    for (int r = 0; r < 4; ++r) {
      int srow = qb * 64 + wave * 16 + lgrp * 4 + r;
      float val = o[n][r] / lsum[r];
      ctx[(size_t)srow * HIDDEN + col] = f32_bf16(val);
    }
  }
}

extern "C" void kernel_launch(void* const* d_in, const int* in_sizes, int n_in,
                              void* d_out, int out_size, void* d_ws, size_t ws_size,
                              hipStream_t stream) {
  const float* hidden  = (const float*)d_in[0];  // [1][SEQ][HIDDEN]
  const float* w_qkv   = (const float*)d_in[1];  // [QKV_OUT][HIDDEN]
  const float* b_qkv   = (const float*)d_in[2];  // [QKV_OUT]
  const float* w_dense = (const float*)d_in[3];  // [HIDDEN][HIDDEN]
  const float* b_dense = (const float*)d_in[4];  // [HIDDEN]
  float* out = (float*)d_out;

  char* p = (char*)d_ws;
  unsigned short* hid_bf  = (unsigned short*)p; p += (size_t)SEQ * HIDDEN * 2;      // 16MB (reused as ctx)
  unsigned short* wqkv_bf = (unsigned short*)p; p += (size_t)QKV_OUT * HIDDEN * 2;  // 48MB
  unsigned short* wd_bf   = (unsigned short*)p; p += (size_t)HIDDEN * HIDDEN * 2;   // 32MB
  float* qkv              = (float*)p;          p += (size_t)SEQ * QKV_OUT * 4;     // 48MB
  unsigned short* Qb      = (unsigned short*)p; p += (size_t)NH * SEQ * HD * 2;     // 16MB
  unsigned short* Kb      = (unsigned short*)p; p += (size_t)NKV * SEQ * HD * 2;    // 4MB
  unsigned short* Vt      = (unsigned short*)p; p += (size_t)NKV * HD * SEQ * 2;    // 4MB
  float* ct               = (float*)p;          p += (size_t)SEQ * 64 * 4;
  float* st               = (float*)p;          p += (size_t)SEQ * 64 * 4;
  unsigned short* ctx = hid_bf;  // hidden_bf16 is dead after the QKV GEMM

  conv_bf16<<<(SEQ * HIDDEN) / 2048, 256, 0, stream>>>(hidden, hid_bf, SEQ * HIDDEN);
  conv_bf16<<<(QKV_OUT * HIDDEN) / 2048, 256, 0, stream>>>(w_qkv, wqkv_bf, QKV_OUT * HIDDEN);
  conv_bf16<<<(HIDDEN * HIDDEN) / 2048, 256, 0, stream>>>(w_dense, wd_bf, HIDDEN * HIDDEN);
  build_tab<<<(SEQ * 64) / 256, 256, 0, stream>>>(ct, st);

  gemm_bt<<<dim3(QKV_OUT / 128, SEQ / 128), 256, 0, stream>>>(
      hid_bf, wqkv_bf, b_qkv, qkv, SEQ, QKV_OUT, HIDDEN);
  rope_split<<<(SEQ * 48 * 128) / 256, 256, 0, stream>>>(qkv, ct, st, Qb, Kb, Vt);
  attn<<<dim3(NH, SEQ / 64), 256, 0, stream>>>(Qb, Kb, Vt, ctx);
  gemm_bt<<<dim3(HIDDEN / 128, SEQ / 128), 256, 0, stream>>>(
      ctx, wd_bf, b_dense, out, SEQ, HIDDEN, HIDDEN);
}

// Round 2
// 498.909 us; speedup vs baseline: 1.0673x; 1.0673x over previous
//
#include <hip/hip_runtime.h>

#define SEQ 2048
#define HIDDEN 4096
#define NH 32
#define NKV 8
#define HD 128
#define QKV_OUT 6144   // (32 + 2*8) * 128
// Q is pre-scaled by SM_SCALE*log2(e) so softmax uses exp2 directly.
#define QSCALE (0.0078125f * 1.4426950408889634f)

typedef __attribute__((ext_vector_type(8))) short bf16x8;
typedef __attribute__((ext_vector_type(4))) short s16x4;
typedef __attribute__((ext_vector_type(4))) float f32x4;

__device__ inline unsigned short f32_bf16(float f) {
  union { float f; unsigned int u; } v; v.f = f;
  unsigned int r = v.u + 0x7FFFu + ((v.u >> 16) & 1u);
  return (unsigned short)(r >> 16);
}
__device__ inline unsigned int pack_bf16(float a, float b) {
  union { float f; unsigned int u; } x, y; x.f = a; y.f = b;
  unsigned int ra = x.u + 0x7FFFu + ((x.u >> 16) & 1u);
  unsigned int rb = y.u + 0x7FFFu + ((y.u >> 16) & 1u);
  return (ra >> 16) | (rb & 0xFFFF0000u);
}
__device__ inline s16x4 pack4_bf16(float a, float b, float c, float d) {
  union { unsigned int u[2]; s16x4 v; } t;
  t.u[0] = pack_bf16(a, b); t.u[1] = pack_bf16(c, d);
  return t.v;
}

// ---------------- fp32 -> bf16 bulk conversion ----------------
__global__ __launch_bounds__(256) void conv_bf16(const float* __restrict__ in,
                                                 unsigned short* __restrict__ out,
                                                 int n) {
  int i = (blockIdx.x * 256 + threadIdx.x) * 8;
  if (i + 8 > n) return;
  float4 a = *reinterpret_cast<const float4*>(in + i);
  float4 b = *reinterpret_cast<const float4*>(in + i + 4);
  unsigned short t[8];
  t[0] = f32_bf16(a.x); t[1] = f32_bf16(a.y); t[2] = f32_bf16(a.z); t[3] = f32_bf16(a.w);
  t[4] = f32_bf16(b.x); t[5] = f32_bf16(b.y); t[6] = f32_bf16(b.z); t[7] = f32_bf16(b.w);
  *reinterpret_cast<uint4*>(out + i) = *reinterpret_cast<uint4*>(t);
}

// ---------------- RoPE cos/sin tables [SEQ][64] ----------------
__global__ __launch_bounds__(256) void build_tab(float* __restrict__ ct,
                                                 float* __restrict__ st) {
  int idx = blockIdx.x * 256 + threadIdx.x;  // SEQ*64
  int s = idx >> 6, d = idx & 63;
  float inv = powf(1.0e6f, -(float)d * (1.0f / 64.0f));
  float f = (float)s * inv;
  ct[idx] = cosf(f);
  st[idx] = sinf(f);
}

// ---------------- GEMM: C[M,N] = A[M,K] * B[N,K]^T + bias ----------------
// m97 structure: global_load_lds width-16, linear LDS [128][32].
__global__ __launch_bounds__(256) void gemm_bt(const unsigned short* __restrict__ A,
                                               const unsigned short* __restrict__ B,
                                               const float* __restrict__ bias,
                                               float* __restrict__ C,
                                               int M, int N, int K) {
  __shared__ unsigned short As[128][32];
  __shared__ unsigned short Bs[128][32];
  const int tid = threadIdx.x;
  const int wave = tid >> 6, lane = tid & 63;
  const int wr = wave >> 1, wc = wave & 1;
  const int lrow = lane & 15, lgrp = lane >> 4;
  const int bm = blockIdx.y * 128, bn = blockIdx.x * 128;
  // staging: wave w covers rows [w*32, w*32+32) of both tiles, 2 loads each.
  const int srow = wave * 32 + (lane >> 2);
  const int scol = (lane & 3) * 8;
  const unsigned short* ga = A + (size_t)(bm + srow) * K + scol;
  const unsigned short* gb = B + (size_t)(bn + srow) * K + scol;
  auto* lA0 = (__attribute__((address_space(3))) unsigned int*)&As[wave * 32][0];
  auto* lA1 = (__attribute__((address_space(3))) unsigned int*)&As[wave * 32 + 16][0];
  auto* lB0 = (__attribute__((address_space(3))) unsigned int*)&Bs[wave * 32][0];
  auto* lB1 = (__attribute__((address_space(3))) unsigned int*)&Bs[wave * 32 + 16][0];
  f32x4 acc[4][4] = {};

  for (int k0 = 0; k0 < K; k0 += 32) {
    __builtin_amdgcn_global_load_lds(
        (const __attribute__((address_space(1))) unsigned int*)(ga + k0), lA0, 16, 0, 0);
    __builtin_amdgcn_global_load_lds(
        (const __attribute__((address_space(1))) unsigned int*)(ga + (size_t)16 * K + k0), lA1, 16, 0, 0);
    __builtin_amdgcn_global_load_lds(
        (const __attribute__((address_space(1))) unsigned int*)(gb + k0), lB0, 16, 0, 0);
    __builtin_amdgcn_global_load_lds(
        (const __attribute__((address_space(1))) unsigned int*)(gb + (size_t)16 * K + k0), lB1, 16, 0, 0);
    __syncthreads();
    bf16x8 a[4], b[4];
#pragma unroll
    for (int m = 0; m < 4; ++m)
      a[m] = *reinterpret_cast<const bf16x8*>(&As[wr * 64 + m * 16 + lrow][lgrp * 8]);
#pragma unroll
    for (int n = 0; n < 4; ++n)
      b[n] = *reinterpret_cast<const bf16x8*>(&Bs[wc * 64 + n * 16 + lrow][lgrp * 8]);
#pragma unroll
    for (int m = 0; m < 4; ++m)
#pragma unroll
      for (int n = 0; n < 4; ++n)
        acc[m][n] = __builtin_amdgcn_mfma_f32_16x16x32_bf16(a[m], b[n], acc[m][n], 0, 0, 0);
    __syncthreads();
  }
#pragma unroll
  for (int m = 0; m < 4; ++m)
#pragma unroll
    for (int n = 0; n < 4; ++n) {
      int col = bn + wc * 64 + n * 16 + lrow;
      float bv = bias[col];
#pragma unroll
      for (int r = 0; r < 4; ++r) {
        int row = bm + wr * 64 + m * 16 + lgrp * 4 + r;
        C[(size_t)row * N + col] = acc[m][n][r] + bv;
      }
    }
}

// ---------------- RoPE + split into Q / K / V^T (bf16) ----------------
// Q additionally pre-scaled by SM_SCALE*log2e.
__global__ __launch_bounds__(256) void rope_split(const float* __restrict__ qkv,
                                                  const float* __restrict__ ct,
                                                  const float* __restrict__ st,
                                                  unsigned short* __restrict__ Q,
                                                  unsigned short* __restrict__ Kh,
                                                  unsigned short* __restrict__ Vt) {
  int idx = blockIdx.x * 256 + threadIdx.x;  // SEQ*48*128
  int d = idx & 127;
  int t = idx >> 7;
  int head = t % 48;
  int s = t / 48;
  int gg = head / 6, slot = head - gg * 6;
  const float* base = qkv + (size_t)s * QKV_OUT + gg * 768 + slot * 128;
  float x = base[d];
  if (slot == 5) {
    Vt[((size_t)gg * HD + d) * SEQ + s] = f32_bf16(x);
  } else {
    int dm = d & 63;
    float c = ct[s * 64 + dm], sn = st[s * 64 + dm];
    float rot = (d < 64) ? -base[d + 64] : base[d - 64];
    float val = x * c + rot * sn;
    if (slot < 4)
      Q[((size_t)(gg * 4 + slot) * SEQ + s) * HD + d] = f32_bf16(val * QSCALE);
    else
      Kh[((size_t)gg * SEQ + s) * HD + d] = f32_bf16(val);
  }
}

// ---------------- blocksparse flash attention (swapped-operand) ----------------
// grid = (NH, SEQ/64), qb reversed (longest first). 4 waves x 16 q-rows.
// QK^T computed as mfma(K,Q): lane holds P^T[k][q], q = lane&15 (one q-row/lane).
// PV computed as O^T = mfma(Vt, P^T). Epilogue transposes O^T via swizzled LDS.
__global__ __launch_bounds__(256) void attn(const unsigned short* __restrict__ Q,
                                            const unsigned short* __restrict__ Kh,
                                            const unsigned short* __restrict__ Vt,
                                            unsigned short* __restrict__ ctx) {
  const int h = blockIdx.x;
  const int qb = (int)(gridDim.y - 1) - (int)blockIdx.y;
  const int g = h >> 2;
  const int wave = threadIdx.x >> 6, lane = threadIdx.x & 63;
  const int q = lane & 15, lgrp = lane >> 4;
  __shared__ unsigned short SB[4][2048];  // per-wave: P^T [16][64] then O^T [16][128], XOR-swizzled
  unsigned short* W = SB[wave];
  const int swz = (q & 7) << 3;

  bf16x8 qf[4];  // B-operand: col=q, k(head-dim)=8*lgrp+e
  const unsigned short* qbase = Q + ((size_t)h * SEQ + (size_t)qb * 64 + wave * 16 + q) * HD;
#pragma unroll
  for (int kk = 0; kk < 4; ++kk)
    qf[kk] = *reinterpret_cast<const bf16x8*>(qbase + kk * 32 + lgrp * 8);

  f32x4 o[8] = {};                 // O^T: d = n2*16+4*lgrp+r, col = q
  float mrow = -1e30f, lsum = 0.f;

  for (int j = 0; j <= qb; ++j) {
    if (!((qb - j) < 16 || ((j + 1) & 7) == 0)) continue;

    // S^T = K * Q^T : A = K-frag (row = k-pos), B = Q-frag (col = q)
    f32x4 s[4] = {};
#pragma unroll
    for (int kk = 0; kk < 4; ++kk) {
#pragma unroll
      for (int n = 0; n < 4; ++n) {
        bf16x8 kf = *reinterpret_cast<const bf16x8*>(
            Kh + ((size_t)g * SEQ + (size_t)j * 64 + n * 16 + q) * HD + kk * 32 + lgrp * 8);
        s[n] = __builtin_amdgcn_mfma_f32_16x16x32_bf16(kf, qf[kk], s[n], 0, 0, 0);
      }
    }
    // s[n][r]: k_in = n*16 + 4*lgrp + r (already in log2 domain via QSCALE)
    if (j == qb) {
      int qg = wave * 16 + q;
#pragma unroll
      for (int n = 0; n < 4; ++n)
#pragma unroll
        for (int r = 0; r < 4; ++r)
          if (n * 16 + 4 * lgrp + r > qg) s[n][r] = -1e30f;
    }
    // online softmax: one q-row per lane; combine 4 lane-groups with 2 shuffles
    float vm = fmaxf(fmaxf(fmaxf(s[0][0], s[0][1]), fmaxf(s[0][2], s[0][3])),
                     fmaxf(fmaxf(s[1][0], s[1][1]), fmaxf(s[1][2], s[1][3])));
    vm = fmaxf(vm, fmaxf(fmaxf(fmaxf(s[2][0], s[2][1]), fmaxf(s[2][2], s[2][3])),
                         fmaxf(fmaxf(s[3][0], s[3][1]), fmaxf(s[3][2], s[3][3]))));
    vm = fmaxf(vm, __shfl_xor(vm, 16));
    vm = fmaxf(vm, __shfl_xor(vm, 32));
    float nm = fmaxf(mrow, vm);
    float corr = __builtin_amdgcn_exp2f(mrow - nm);
    mrow = nm;
    float ps = 0.f;
#pragma unroll
    for (int n = 0; n < 4; ++n)
#pragma unroll
      for (int r = 0; r < 4; ++r) {
        float p = __builtin_amdgcn_exp2f(s[n][r] - nm);
        s[n][r] = p;
        ps += p;
      }
    ps += __shfl_xor(ps, 16);
    ps += __shfl_xor(ps, 32);
    lsum = lsum * corr + ps;
#pragma unroll
    for (int n2 = 0; n2 < 8; ++n2)
#pragma unroll
      for (int r = 0; r < 4; ++r) o[n2][r] *= corr;

    // P^T -> LDS, packed b64, XOR-swizzled (conflict-free)
#pragma unroll
    for (int n = 0; n < 4; ++n)
      *reinterpret_cast<s16x4*>(&W[q * 64 + ((n * 16 + 4 * lgrp) ^ swz)]) =
          pack4_bf16(s[n][0], s[n][1], s[n][2], s[n][3]);

    // O^T += Vt-frag * P^T-frag
#pragma unroll
    for (int c = 0; c < 2; ++c) {
      bf16x8 pb = *reinterpret_cast<const bf16x8*>(&W[q * 64 + ((c * 32 + lgrp * 8) ^ swz)]);
#pragma unroll
      for (int n2 = 0; n2 < 8; ++n2) {
        bf16x8 vf = *reinterpret_cast<const bf16x8*>(
            Vt + ((size_t)g * HD + n2 * 16 + q) * SEQ + (size_t)j * 64 + c * 32 + lgrp * 8);
        o[n2] = __builtin_amdgcn_mfma_f32_16x16x32_bf16(vf, pb, o[n2], 0, 0, 0);
      }
    }
  }

  // epilogue: normalize, transpose O^T via swizzled LDS, coalesced bf16 stores
  float inv = 1.0f / lsum;
#pragma unroll
  for (int n2 = 0; n2 < 8; ++n2)
    *reinterpret_cast<s16x4*>(&W[q * 128 + ((n2 * 16 + 4 * lgrp) ^ swz)]) =
        pack4_bf16(o[n2][0] * inv, o[n2][1] * inv, o[n2][2] * inv, o[n2][3] * inv);
  // wave-local LDS: write->read ordered by lgkmcnt, no barrier needed
#pragma unroll
  for (int i = 0; i < 4; ++i) {
    int row = i * 4 + lgrp;
    bf16x8 vv = *reinterpret_cast<const bf16x8*>(&W[row * 128 + ((q * 8) ^ ((row & 7) << 3))]);
    *reinterpret_cast<bf16x8*>(
        &ctx[(size_t)(qb * 64 + wave * 16 + row) * HIDDEN + h * HD + q * 8]) = vv;
  }
}

extern "C" void kernel_launch(void* const* d_in, const int* in_sizes, int n_in,
                              void* d_out, int out_size, void* d_ws, size_t ws_size,
                              hipStream_t stream) {
  const float* hidden  = (const float*)d_in[0];
  const float* w_qkv   = (const float*)d_in[1];
  const float* b_qkv   = (const float*)d_in[2];
  const float* w_dense = (const float*)d_in[3];
  const float* b_dense = (const float*)d_in[4];
  float* out = (float*)d_out;

  char* p = (char*)d_ws;
  unsigned short* hid_bf  = (unsigned short*)p; p += (size_t)SEQ * HIDDEN * 2;
  unsigned short* wqkv_bf = (unsigned short*)p; p += (size_t)QKV_OUT * HIDDEN * 2;
  unsigned short* wd_bf   = (unsigned short*)p; p += (size_t)HIDDEN * HIDDEN * 2;
  float* qkv              = (float*)p;          p += (size_t)SEQ * QKV_OUT * 4;
  unsigned short* Qb      = (unsigned short*)p; p += (size_t)NH * SEQ * HD * 2;
  unsigned short* Kb      = (unsigned short*)p; p += (size_t)NKV * SEQ * HD * 2;
  unsigned short* Vt      = (unsigned short*)p; p += (size_t)NKV * HD * SEQ * 2;
  float* ct               = (float*)p;          p += (size_t)SEQ * 64 * 4;
  float* st               = (float*)p;          p += (size_t)SEQ * 64 * 4;
  unsigned short* ctx = hid_bf;  // hidden_bf16 dead after QKV GEMM

  conv_bf16<<<(SEQ * HIDDEN) / 2048, 256, 0, stream>>>(hidden, hid_bf, SEQ * HIDDEN);
  conv_bf16<<<(QKV_OUT * HIDDEN) / 2048, 256, 0, stream>>>(w_qkv, wqkv_bf, QKV_OUT * HIDDEN);
  conv_bf16<<<(HIDDEN * HIDDEN) / 2048, 256, 0, stream>>>(w_dense, wd_bf, HIDDEN * HIDDEN);
  build_tab<<<(SEQ * 64) / 256, 256, 0, stream>>>(ct, st);

  gemm_bt<<<dim3(QKV_OUT / 128, SEQ / 128), 256, 0, stream>>>(
      hid_bf, wqkv_bf, b_qkv, qkv, SEQ, QKV_OUT, HIDDEN);
  rope_split<<<(SEQ * 48 * 128) / 256, 256, 0, stream>>>(qkv, ct, st, Qb, Kb, Vt);
  attn<<<dim3(NH, SEQ / 64), 256, 0, stream>>>(Qb, Kb, Vt, ctx);
  gemm_bt<<<dim3(HIDDEN / 128, SEQ / 128), 256, 0, stream>>>(
      ctx, wd_bf, b_dense, out, SEQ, HIDDEN, HIDDEN);
}

// Round 3
// 445.365 us; speedup vs baseline: 1.1956x; 1.1202x over previous
//
#include <hip/hip_runtime.h>
#include <hip/hip_bf16.h>

#define SEQ 2048
#define HIDDEN 4096
#define NH 32
#define NKV 8
#define HD 128
#define QKV_OUT 6144   // (32 + 2*8) * 128
// Q is pre-scaled by SM_SCALE*log2(e) so softmax uses exp2 directly.
#define QSCALE (0.0078125f * 1.4426950408889634f)

typedef __attribute__((ext_vector_type(8))) short bf16x8;
typedef __attribute__((ext_vector_type(4))) float f32x4;
typedef __attribute__((ext_vector_type(16))) float f32x16;

__device__ inline unsigned short f32_bf16(float f) {
  union { float f; unsigned int u; } v; v.f = f;
  unsigned int r = v.u + 0x7FFFu + ((v.u >> 16) & 1u);
  return (unsigned short)(r >> 16);
}
__device__ inline unsigned int pk(float a, float b) {
  union { __hip_bfloat162 h; unsigned int u; } t;
  t.h = __float22bfloat162_rn(make_float2(a, b));
  return t.u;
}
// permlane32_swap wrappers. pswap: a' = {a.lo-half, b.lo-half}, b' = {a.hi, b.hi}
__device__ inline void pswap(unsigned int &a, unsigned int &b) {
  auto r = __builtin_amdgcn_permlane32_swap((int)a, (int)b, false, false);
  a = (unsigned int)r[0]; b = (unsigned int)r[1];
}
__device__ inline float xmax32(float v) {  // max with partner lane (lane^32)
  int x = __builtin_bit_cast(int, v);
  auto r = __builtin_amdgcn_permlane32_swap(x, x, false, false);
  return fmaxf(__builtin_bit_cast(float, (int)r[0]), __builtin_bit_cast(float, (int)r[1]));
}
__device__ inline float xadd32(float v) {
  int x = __builtin_bit_cast(int, v);
  auto r = __builtin_amdgcn_permlane32_swap(x, x, false, false);
  return __builtin_bit_cast(float, (int)r[0]) + __builtin_bit_cast(float, (int)r[1]);
}

// ---------------- fp32 -> bf16 bulk conversion ----------------
__global__ __launch_bounds__(256) void conv_bf16(const float* __restrict__ in,
                                                 unsigned short* __restrict__ out,
                                                 int n) {
  int i = (blockIdx.x * 256 + threadIdx.x) * 8;
  if (i + 8 > n) return;
  float4 a = *reinterpret_cast<const float4*>(in + i);
  float4 b = *reinterpret_cast<const float4*>(in + i + 4);
  unsigned short t[8];
  t[0] = f32_bf16(a.x); t[1] = f32_bf16(a.y); t[2] = f32_bf16(a.z); t[3] = f32_bf16(a.w);
  t[4] = f32_bf16(b.x); t[5] = f32_bf16(b.y); t[6] = f32_bf16(b.z); t[7] = f32_bf16(b.w);
  *reinterpret_cast<uint4*>(out + i) = *reinterpret_cast<uint4*>(t);
}

// ---------------- RoPE cos/sin tables [SEQ][64] ----------------
__global__ __launch_bounds__(256) void build_tab(float* __restrict__ ct,
                                                 float* __restrict__ st) {
  int idx = blockIdx.x * 256 + threadIdx.x;  // SEQ*64
  int s = idx >> 6, d = idx & 63;
  float inv = powf(1.0e6f, -(float)d * (1.0f / 64.0f));
  float f = (float)s * inv;
  ct[idx] = cosf(f);
  st[idx] = sinf(f);
}

// ---------------- GEMM: C[M,N] = A[M,K] * B[N,K]^T + bias ----------------
// m97 structure: global_load_lds width-16, linear LDS [128][32].
__global__ __launch_bounds__(256) void gemm_bt(const unsigned short* __restrict__ A,
                                               const unsigned short* __restrict__ B,
                                               const float* __restrict__ bias,
                                               float* __restrict__ C,
                                               int M, int N, int K) {
  __shared__ unsigned short As[128][32];
  __shared__ unsigned short Bs[128][32];
  const int tid = threadIdx.x;
  const int wave = tid >> 6, lane = tid & 63;
  const int wr = wave >> 1, wc = wave & 1;
  const int lrow = lane & 15, lgrp = lane >> 4;
  const int bm = blockIdx.y * 128, bn = blockIdx.x * 128;
  const int srow = wave * 32 + (lane >> 2);
  const int scol = (lane & 3) * 8;
  const unsigned short* ga = A + (size_t)(bm + srow) * K + scol;
  const unsigned short* gb = B + (size_t)(bn + srow) * K + scol;
  auto* lA0 = (__attribute__((address_space(3))) unsigned int*)&As[wave * 32][0];
  auto* lA1 = (__attribute__((address_space(3))) unsigned int*)&As[wave * 32 + 16][0];
  auto* lB0 = (__attribute__((address_space(3))) unsigned int*)&Bs[wave * 32][0];
  auto* lB1 = (__attribute__((address_space(3))) unsigned int*)&Bs[wave * 32 + 16][0];
  f32x4 acc[4][4] = {};

  for (int k0 = 0; k0 < K; k0 += 32) {
    __builtin_amdgcn_global_load_lds(
        (const __attribute__((address_space(1))) unsigned int*)(ga + k0), lA0, 16, 0, 0);
    __builtin_amdgcn_global_load_lds(
        (const __attribute__((address_space(1))) unsigned int*)(ga + (size_t)16 * K + k0), lA1, 16, 0, 0);
    __builtin_amdgcn_global_load_lds(
        (const __attribute__((address_space(1))) unsigned int*)(gb + k0), lB0, 16, 0, 0);
    __builtin_amdgcn_global_load_lds(
        (const __attribute__((address_space(1))) unsigned int*)(gb + (size_t)16 * K + k0), lB1, 16, 0, 0);
    __syncthreads();
    bf16x8 a[4], b[4];
#pragma unroll
    for (int m = 0; m < 4; ++m)
      a[m] = *reinterpret_cast<const bf16x8*>(&As[wr * 64 + m * 16 + lrow][lgrp * 8]);
#pragma unroll
    for (int n = 0; n < 4; ++n)
      b[n] = *reinterpret_cast<const bf16x8*>(&Bs[wc * 64 + n * 16 + lrow][lgrp * 8]);
#pragma unroll
    for (int m = 0; m < 4; ++m)
#pragma unroll
      for (int n = 0; n < 4; ++n)
        acc[m][n] = __builtin_amdgcn_mfma_f32_16x16x32_bf16(a[m], b[n], acc[m][n], 0, 0, 0);
    __syncthreads();
  }
#pragma unroll
  for (int m = 0; m < 4; ++m)
#pragma unroll
    for (int n = 0; n < 4; ++n) {
      int col = bn + wc * 64 + n * 16 + lrow;
      float bv = bias[col];
#pragma unroll
      for (int r = 0; r < 4; ++r) {
        int row = bm + wr * 64 + m * 16 + lgrp * 4 + r;
        C[(size_t)row * N + col] = acc[m][n][r] + bv;
      }
    }
}

// ---------------- RoPE + split into Q / K / V^T (bf16) ----------------
__global__ __launch_bounds__(256) void rope_split(const float* __restrict__ qkv,
                                                  const float* __restrict__ ct,
                                                  const float* __restrict__ st,
                                                  unsigned short* __restrict__ Q,
                                                  unsigned short* __restrict__ Kh,
                                                  unsigned short* __restrict__ Vt) {
  int idx = blockIdx.x * 256 + threadIdx.x;  // SEQ*48*128
  int d = idx & 127;
  int t = idx >> 7;
  int head = t % 48;
  int s = t / 48;
  int gg = head / 6, slot = head - gg * 6;
  const float* base = qkv + (size_t)s * QKV_OUT + gg * 768 + slot * 128;
  float x = base[d];
  if (slot == 5) {
    Vt[((size_t)gg * HD + d) * SEQ + s] = f32_bf16(x);
  } else {
    int dm = d & 63;
    float c = ct[s * 64 + dm], sn = st[s * 64 + dm];
    float rot = (d < 64) ? -base[d + 64] : base[d - 64];
    float val = x * c + rot * sn;
    if (slot < 4)
      Q[((size_t)(gg * 4 + slot) * SEQ + s) * HD + d] = f32_bf16(val * QSCALE);
    else
      Kh[((size_t)gg * SEQ + s) * HD + d] = f32_bf16(val);
  }
}

// ---------------- blocksparse flash attention, 32x32 MFMA, zero-LDS main loop ----
// grid (NKV, SEQ/32) y-reversed; 4 waves = 4 heads of KV group g, same 32 q-rows.
// S^T = mfma32(K,Q): lane holds P[k][q] for q=lane&31; k=(reg&3)+8*(reg>>2)+4*hi (+32*kt).
// Softmax in-register (permlane32_swap cross-half). PV B-frags assembled via
// cvt_pk + permlane32_swap (T12). O^T transposed once via swizzled LDS epilogue.
__global__ __launch_bounds__(256, 2) void attn32(const unsigned short* __restrict__ Q,
                                                 const unsigned short* __restrict__ Kh,
                                                 const unsigned short* __restrict__ Vt,
                                                 unsigned short* __restrict__ ctx) {
  const int g = blockIdx.x;
  const int y = (int)gridDim.y - 1 - (int)blockIdx.y;  // big qb first
  const int qb = y >> 1, half = y & 1;
  const int Q0 = y * 32;
  const int wave = threadIdx.x >> 6;
  const int h = g * 4 + wave;
  const int lane = threadIdx.x & 63;
  const int l31 = lane & 31, hi = lane >> 5;

  __shared__ unsigned short SB[4][32 * 128];  // epilogue transpose only
  char* W = (char*)SB[wave];

  bf16x8 qf[8];  // B-operand: col=q=l31, hd = kk*16 + hi*8 + e
  const unsigned short* qbase = Q + ((size_t)h * SEQ + Q0 + l31) * HD;
#pragma unroll
  for (int kk = 0; kk < 8; ++kk)
    qf[kk] = *reinterpret_cast<const bf16x8*>(qbase + kk * 16 + hi * 8);

  f32x16 ot[4] = {};  // O^T: d = dt*32 + (r&3)+8*(r>>2)+4*hi, col=q
  float mrow = -1e30f, lsum = 0.f;

  for (int j = 0; j <= qb; ++j) {
    if (!((qb - j) < 16 || ((j + 1) & 7) == 0)) continue;
    const bool diag = (j == qb);
    const bool short_blk = diag && (half == 0);  // k-subtile 1 fully masked

    // S^T = K * Q^T (two 32-row k-subtiles)
    f32x16 st[2] = {};
    {
      const unsigned short* kb = Kh + ((size_t)(g * SEQ + j * 64 + l31)) * HD + hi * 8;
#pragma unroll
      for (int kk = 0; kk < 8; ++kk)
        st[0] = __builtin_amdgcn_mfma_f32_32x32x16_bf16(
            *reinterpret_cast<const bf16x8*>(kb + kk * 16), qf[kk], st[0], 0, 0, 0);
    }
    if (!short_blk) {
      const unsigned short* kb = Kh + ((size_t)(g * SEQ + j * 64 + 32 + l31)) * HD + hi * 8;
#pragma unroll
      for (int kk = 0; kk < 8; ++kk)
        st[1] = __builtin_amdgcn_mfma_f32_32x32x16_bf16(
            *reinterpret_cast<const bf16x8*>(kb + kk * 16), qf[kk], st[1], 0, 0, 0);
    }

    if (diag) {  // elementwise causal mask on the diagonal block
      int qrel = half * 32 + l31;
#pragma unroll
      for (int kt = 0; kt < 2; ++kt)
#pragma unroll
        for (int r = 0; r < 16; ++r) {
          int krel = kt * 32 + (r & 3) + 8 * (r >> 2) + 4 * hi;
          if (krel > qrel) st[kt][r] = -1e30f;
        }
    }

    // row max: in-register tree + one permlane swap (log2-domain scores)
    float t16[16];
#pragma unroll
    for (int r = 0; r < 16; ++r) t16[r] = fmaxf(st[0][r], st[1][r]);
#pragma unroll
    for (int sft = 8; sft >= 1; sft >>= 1)
#pragma unroll
      for (int r = 0; r < sft; ++r) t16[r] = fmaxf(t16[r], t16[r + sft]);
    float vm = xmax32(t16[0]);

    // T13 defer-max: only rescale when max grew by > 8 (factor 256)
    if (!__all(vm - mrow <= 8.0f)) {
      float nm = fmaxf(mrow, vm);
      float corr = __builtin_amdgcn_exp2f(mrow - nm);
      lsum *= corr;
#pragma unroll
      for (int dt = 0; dt < 4; ++dt)
#pragma unroll
        for (int r = 0; r < 16; ++r) ot[dt][r] *= corr;
      mrow = nm;
    }

    // P = exp2(S - m), row sum
    float s4[4] = {0.f, 0.f, 0.f, 0.f};
#pragma unroll
    for (int kt = 0; kt < 2; ++kt)
#pragma unroll
      for (int r = 0; r < 16; ++r) {
        float p = __builtin_amdgcn_exp2f(st[kt][r] - mrow);
        st[kt][r] = p;
        s4[r & 3] += p;
      }
    lsum += xadd32((s4[0] + s4[1]) + (s4[2] + s4[3]));

    // T12: P^T B-fragments in-register (4 cvt_pk + 2 permlane per 16-k step)
    bf16x8 pb[4];
#pragma unroll
    for (int s = 0; s < 4; ++s) {
      int kt = s >> 1, g0 = (s & 1) * 2, g1 = g0 + 1;
      unsigned int a0 = pk(st[kt][4 * g0 + 0], st[kt][4 * g0 + 1]);
      unsigned int a1 = pk(st[kt][4 * g0 + 2], st[kt][4 * g0 + 3]);
      unsigned int b0 = pk(st[kt][4 * g1 + 0], st[kt][4 * g1 + 1]);
      unsigned int b1 = pk(st[kt][4 * g1 + 2], st[kt][4 * g1 + 3]);
      pswap(a0, b0);  // a0 -> word0 (k=16s+{0,1}|{8,9}), b0 -> word2
      pswap(a1, b1);  // a1 -> word1, b1 -> word3
      union { unsigned int u[4]; bf16x8 v; } t;
      t.u[0] = a0; t.u[1] = a1; t.u[2] = b0; t.u[3] = b1;
      pb[s] = t.v;
    }

    // O^T += V^T * P^T
    const int smax = short_blk ? 2 : 4;  // dead k-steps on half-0 diagonal
#pragma unroll
    for (int dt = 0; dt < 4; ++dt) {
      const unsigned short* vb =
          Vt + ((size_t)(g * HD + dt * 32 + l31)) * SEQ + j * 64 + hi * 8;
#pragma unroll
      for (int s = 0; s < 4; ++s)
        if (s < smax)
          ot[dt] = __builtin_amdgcn_mfma_f32_32x32x16_bf16(
              *reinterpret_cast<const bf16x8*>(vb + s * 16), pb[s], ot[dt], 0, 0, 0);
    }
  }

  // epilogue: normalize + transpose O^T via XOR-swizzled LDS, 16B stores
  float inv = 1.0f / lsum;
  const int swz = (l31 & 7) << 4;
#pragma unroll
  for (int dt = 0; dt < 4; ++dt)
#pragma unroll
    for (int gg = 0; gg < 4; ++gg) {
      unsigned int u0 = pk(ot[dt][4 * gg + 0] * inv, ot[dt][4 * gg + 1] * inv);
      unsigned int u1 = pk(ot[dt][4 * gg + 2] * inv, ot[dt][4 * gg + 3] * inv);
      int off = (dt * 64 + gg * 16 + hi * 8) ^ swz;  // byte offset within 256B row
      *reinterpret_cast<uint2*>(W + l31 * 256 + off) = make_uint2(u0, u1);
    }
  // wave-local LDS write->read: ordered by lgkmcnt, no barrier needed
#pragma unroll
  for (int i = 0; i < 8; ++i) {
    int row = lane >> 1;
    int t = (lane & 1) * 8 + i;
    bf16x8 vv = *reinterpret_cast<const bf16x8*>(
        W + row * 256 + ((t * 16) ^ ((row & 7) << 4)));
    *reinterpret_cast<bf16x8*>(&ctx[(size_t)(Q0 + row) * HIDDEN + h * HD + t * 8]) = vv;
  }
}

extern "C" void kernel_launch(void* const* d_in, const int* in_sizes, int n_in,
                              void* d_out, int out_size, void* d_ws, size_t ws_size,
                              hipStream_t stream) {
  const float* hidden  = (const float*)d_in[0];
  const float* w_qkv   = (const float*)d_in[1];
  const float* b_qkv   = (const float*)d_in[2];
  const float* w_dense = (const float*)d_in[3];
  const float* b_dense = (const float*)d_in[4];
  float* out = (float*)d_out;

  char* p = (char*)d_ws;
  unsigned short* hid_bf  = (unsigned short*)p; p += (size_t)SEQ * HIDDEN * 2;
  unsigned short* wqkv_bf = (unsigned short*)p; p += (size_t)QKV_OUT * HIDDEN * 2;
  unsigned short* wd_bf   = (unsigned short*)p; p += (size_t)HIDDEN * HIDDEN * 2;
  float* qkv              = (float*)p;          p += (size_t)SEQ * QKV_OUT * 4;
  unsigned short* Qb      = (unsigned short*)p; p += (size_t)NH * SEQ * HD * 2;
  unsigned short* Kb      = (unsigned short*)p; p += (size_t)NKV * SEQ * HD * 2;
  unsigned short* Vt      = (unsigned short*)p; p += (size_t)NKV * HD * SEQ * 2;
  float* ct               = (float*)p;          p += (size_t)SEQ * 64 * 4;
  float* st               = (float*)p;          p += (size_t)SEQ * 64 * 4;
  unsigned short* ctx = hid_bf;  // hidden_bf16 dead after QKV GEMM

  conv_bf16<<<(SEQ * HIDDEN) / 2048, 256, 0, stream>>>(hidden, hid_bf, SEQ * HIDDEN);
  conv_bf16<<<(QKV_OUT * HIDDEN) / 2048, 256, 0, stream>>>(w_qkv, wqkv_bf, QKV_OUT * HIDDEN);
  conv_bf16<<<(HIDDEN * HIDDEN) / 2048, 256, 0, stream>>>(w_dense, wd_bf, HIDDEN * HIDDEN);
  build_tab<<<(SEQ * 64) / 256, 256, 0, stream>>>(ct, st);

  gemm_bt<<<dim3(QKV_OUT / 128, SEQ / 128), 256, 0, stream>>>(
      hid_bf, wqkv_bf, b_qkv, qkv, SEQ, QKV_OUT, HIDDEN);
  rope_split<<<(SEQ * 48 * 128) / 256, 256, 0, stream>>>(qkv, ct, st, Qb, Kb, Vt);
  attn32<<<dim3(NKV, SEQ / 32), 256, 0, stream>>>(Qb, Kb, Vt, ctx);
  gemm_bt<<<dim3(HIDDEN / 128, SEQ / 128), 256, 0, stream>>>(
      ctx, wd_bf, b_dense, out, SEQ, HIDDEN, HIDDEN);
}

// Round 4
// 390.481 us; speedup vs baseline: 1.3637x; 1.1406x over previous
//
#include <hip/hip_runtime.h>
#include <hip/hip_bf16.h>

#define SEQ 2048
#define HIDDEN 4096
#define NH 32
#define NKV 8
#define HD 128
#define QKV_OUT 6144   // (32 + 2*8) * 128
// Q is pre-scaled by SM_SCALE*log2(e) so softmax uses exp2 directly.
#define QSCALE (0.0078125f * 1.4426950408889634f)

typedef __attribute__((ext_vector_type(8))) short bf16x8;
typedef __attribute__((ext_vector_type(4))) float f32x4;
typedef __attribute__((ext_vector_type(16))) float f32x16;

__device__ inline unsigned short f32_bf16(float f) {
  union { float f; unsigned int u; } v; v.f = f;
  unsigned int r = v.u + 0x7FFFu + ((v.u >> 16) & 1u);
  return (unsigned short)(r >> 16);
}
__device__ inline unsigned int pk(float a, float b) {
  union { __hip_bfloat162 h; unsigned int u; } t;
  t.h = __float22bfloat162_rn(make_float2(a, b));
  return t.u;
}
__device__ inline void pswap(unsigned int &a, unsigned int &b) {
  auto r = __builtin_amdgcn_permlane32_swap((int)a, (int)b, false, false);
  a = (unsigned int)r[0]; b = (unsigned int)r[1];
}
__device__ inline float xmax32(float v) {
  int x = __builtin_bit_cast(int, v);
  auto r = __builtin_amdgcn_permlane32_swap(x, x, false, false);
  return fmaxf(__builtin_bit_cast(float, (int)r[0]), __builtin_bit_cast(float, (int)r[1]));
}
__device__ inline float xadd32(float v) {
  int x = __builtin_bit_cast(int, v);
  auto r = __builtin_amdgcn_permlane32_swap(x, x, false, false);
  return __builtin_bit_cast(float, (int)r[0]) + __builtin_bit_cast(float, (int)r[1]);
}

// ---------------- fp32 -> bf16 bulk conversion ----------------
__global__ __launch_bounds__(256) void conv_bf16(const float* __restrict__ in,
                                                 unsigned short* __restrict__ out,
                                                 int n) {
  int i = (blockIdx.x * 256 + threadIdx.x) * 8;
  if (i + 8 > n) return;
  float4 a = *reinterpret_cast<const float4*>(in + i);
  float4 b = *reinterpret_cast<const float4*>(in + i + 4);
  unsigned short t[8];
  t[0] = f32_bf16(a.x); t[1] = f32_bf16(a.y); t[2] = f32_bf16(a.z); t[3] = f32_bf16(a.w);
  t[4] = f32_bf16(b.x); t[5] = f32_bf16(b.y); t[6] = f32_bf16(b.z); t[7] = f32_bf16(b.w);
  *reinterpret_cast<uint4*>(out + i) = *reinterpret_cast<uint4*>(t);
}

// ---------------- RoPE cos/sin tables [SEQ][64] ----------------
__global__ __launch_bounds__(256) void build_tab(float* __restrict__ ct,
                                                 float* __restrict__ st) {
  int idx = blockIdx.x * 256 + threadIdx.x;  // SEQ*64
  int s = idx >> 6, d = idx & 63;
  float inv = powf(1.0e6f, -(float)d * (1.0f / 64.0f));
  float f = (float)s * inv;
  ct[idx] = cosf(f);
  st[idx] = sinf(f);
}

// ---------------- 4-phase K-sliced GEMM: C[M,N] = A[M,K]*B[N,K]^T + bias ----
// 512 threads = 8 waves (2M x 4N). LDS dbuf, each buf = 2 k-slices of
// {A[BM][32], B[BN][32]} bf16, st_16x32-style XOR swizzle (bit5 ^= row-bit3).
// Stage = global_load_lds w16 with pre-swizzled global source; counted vmcnt
// (2 slices in flight), 1 barrier/phase, setprio around MFMA cluster.
template <int BM, int BN, int LA, int LB>
__global__ __launch_bounds__(512, 2) void gemm8(const unsigned short* __restrict__ A,
                                                const unsigned short* __restrict__ B,
                                                const float* __restrict__ bias,
                                                float* __restrict__ C,
                                                int M, int N, int K) {
  constexpr int MREP = BM / 32;          // frags per wave (M)
  constexpr int NREP = BN / 64;          // frags per wave (N)
  constexpr int HALF = (BM + BN) * 64;   // bytes per k-slice {A,B}
  constexpr int BUF = HALF * 2;          // bytes per k-tile buffer
  constexpr int LP = LA + LB;            // gloads per wave per slice
  __shared__ __align__(16) char Lds[BUF * 2];

  const int tid = threadIdx.x;
  const int wave = tid >> 6, lane = tid & 63;
  const int wr = wave >> 2, wc = wave & 3;
  const int lrow = lane & 15, lgrp = lane >> 4;

  // XCD-aware remap (nwg divisible by 8 for both instantiations)
  const int nwg = gridDim.x;
  const int wg0 = blockIdx.x;
  const int wg = (wg0 & 7) * (nwg >> 3) + (wg0 >> 3);
  const int ntx = N / BN;
  const int bm = (wg / ntx) * BM, bn = (wg % ntx) * BN;

  // staging source (per-lane, pre-swizzled: lanes>=32 swap 16B chunks 0<->2,1<->3)
  const int srow = lane >> 2;
  const int scol = ((lane & 3) ^ ((lane >= 32) ? 2 : 0)) * 8;
  const unsigned short* gA = A + (size_t)(bm + wave * (BM / 8) + srow) * K + scol;
  const unsigned short* gB = B + (size_t)(bn + wave * (BN / 8) + srow) * K + scol;
  const int ldsAw = wave * (BM / 8) * 64;
  const int ldsBw = BM * 64 + wave * (BN / 8) * 64;

  auto stage = [&](int bufb, int h, int k0) {
#pragma unroll
    for (int i = 0; i < LA; ++i)
      __builtin_amdgcn_global_load_lds(
          (const __attribute__((address_space(1))) unsigned int*)(gA + (size_t)(i * 16) * K + k0 + h * 32),
          (__attribute__((address_space(3))) unsigned int*)(Lds + bufb + h * HALF + ldsAw + i * 1024),
          16, 0, 0);
#pragma unroll
    for (int i = 0; i < LB; ++i)
      __builtin_amdgcn_global_load_lds(
          (const __attribute__((address_space(1))) unsigned int*)(gB + (size_t)(i * 16) * K + k0 + h * 32),
          (__attribute__((address_space(3))) unsigned int*)(Lds + bufb + h * HALF + ldsBw + i * 1024),
          16, 0, 0);
  };

  // frag read offsets (XOR bit5 by lrow-bit3 — matches staged permutation)
  const int flip = ((lrow >> 3) & 1) << 5;
  const int aoff = (wr * (BM / 2) + lrow) * 64 + ((lgrp * 16) ^ flip);
  const int boff = BM * 64 + (wc * (BN / 4) + lrow) * 64 + ((lgrp * 16) ^ flip);

  f32x4 acc[MREP][NREP] = {};

  auto phase = [&](int cur, int h) {
    const char* base = Lds + cur + h * HALF;
    bf16x8 af[MREP], bfr[NREP];
#pragma unroll
    for (int m = 0; m < MREP; ++m)
      af[m] = *reinterpret_cast<const bf16x8*>(base + aoff + m * 1024);
#pragma unroll
    for (int n = 0; n < NREP; ++n)
      bfr[n] = *reinterpret_cast<const bf16x8*>(base + boff + n * 1024);
    __builtin_amdgcn_s_setprio(1);
#pragma unroll
    for (int m = 0; m < MREP; ++m)
#pragma unroll
      for (int n = 0; n < NREP; ++n)
        acc[m][n] = __builtin_amdgcn_mfma_f32_16x16x32_bf16(af[m], bfr[n], acc[m][n], 0, 0, 0);
    __builtin_amdgcn_s_setprio(0);
  };

  const int nt = K / 64;
  // prologue: both slices of tile 0 into buf 0
  stage(0, 0, 0);
  stage(0, 1, 0);
  for (int t = 0; t < nt - 1; ++t) {
    const int cur = (t & 1) ? BUF : 0;
    const int nxt = cur ^ BUF;
    const int k1 = (t + 1) * 64;
#pragma unroll
    for (int h = 0; h < 2; ++h) {
      stage(nxt, h, k1);
      if constexpr (LP == 4) asm volatile("s_waitcnt vmcnt(8)" ::: "memory");
      else                   asm volatile("s_waitcnt vmcnt(6)" ::: "memory");
      __builtin_amdgcn_s_barrier();
      asm volatile("" ::: "memory");
      phase(cur, h);
    }
  }
  {  // tail tile (nothing left to stage)
    const int cur = ((nt - 1) & 1) ? BUF : 0;
    if constexpr (LP == 4) asm volatile("s_waitcnt vmcnt(4)" ::: "memory");
    else                   asm volatile("s_waitcnt vmcnt(3)" ::: "memory");
    __builtin_amdgcn_s_barrier();
    asm volatile("" ::: "memory");
    phase(cur, 0);
    asm volatile("s_waitcnt vmcnt(0)" ::: "memory");
    __builtin_amdgcn_s_barrier();
    asm volatile("" ::: "memory");
    phase(cur, 1);
  }

  // epilogue: bias + fp32 store
#pragma unroll
  for (int n = 0; n < NREP; ++n) {
    int col = bn + wc * (BN / 4) + n * 16 + lrow;
    float bv = bias[col];
#pragma unroll
    for (int m = 0; m < MREP; ++m)
#pragma unroll
      for (int r = 0; r < 4; ++r) {
        int row = bm + wr * (BM / 2) + m * 16 + lgrp * 4 + r;
        C[(size_t)row * N + col] = acc[m][n][r] + bv;
      }
  }
}

// ---------------- RoPE + split into Q / K / V^T (bf16) ----------------
__global__ __launch_bounds__(256) void rope_split(const float* __restrict__ qkv,
                                                  const float* __restrict__ ct,
                                                  const float* __restrict__ st,
                                                  unsigned short* __restrict__ Q,
                                                  unsigned short* __restrict__ Kh,
                                                  unsigned short* __restrict__ Vt) {
  int idx = blockIdx.x * 256 + threadIdx.x;  // SEQ*48*128
  int d = idx & 127;
  int t = idx >> 7;
  int head = t % 48;
  int s = t / 48;
  int gg = head / 6, slot = head - gg * 6;
  const float* base = qkv + (size_t)s * QKV_OUT + gg * 768 + slot * 128;
  float x = base[d];
  if (slot == 5) {
    Vt[((size_t)gg * HD + d) * SEQ + s] = f32_bf16(x);
  } else {
    int dm = d & 63;
    float c = ct[s * 64 + dm], sn = st[s * 64 + dm];
    float rot = (d < 64) ? -base[d + 64] : base[d - 64];
    float val = x * c + rot * sn;
    if (slot < 4)
      Q[((size_t)(gg * 4 + slot) * SEQ + s) * HD + d] = f32_bf16(val * QSCALE);
    else
      Kh[((size_t)gg * SEQ + s) * HD + d] = f32_bf16(val);
  }
}

// ---------------- blocksparse flash attention, 32x32 MFMA, zero-LDS main loop ----
__global__ __launch_bounds__(256, 2) void attn32(const unsigned short* __restrict__ Q,
                                                 const unsigned short* __restrict__ Kh,
                                                 const unsigned short* __restrict__ Vt,
                                                 unsigned short* __restrict__ ctx) {
  const int g = blockIdx.x;
  const int y = (int)gridDim.y - 1 - (int)blockIdx.y;  // big qb first
  const int qb = y >> 1, half = y & 1;
  const int Q0 = y * 32;
  const int wave = threadIdx.x >> 6;
  const int h = g * 4 + wave;
  const int lane = threadIdx.x & 63;
  const int l31 = lane & 31, hi = lane >> 5;

  __shared__ unsigned short SB[4][32 * 128];  // epilogue transpose only
  char* W = (char*)SB[wave];

  bf16x8 qf[8];  // B-operand: col=q=l31, hd = kk*16 + hi*8 + e
  const unsigned short* qbase = Q + ((size_t)h * SEQ + Q0 + l31) * HD;
#pragma unroll
  for (int kk = 0; kk < 8; ++kk)
    qf[kk] = *reinterpret_cast<const bf16x8*>(qbase + kk * 16 + hi * 8);

  f32x16 ot[4] = {};  // O^T: d = dt*32 + (r&3)+8*(r>>2)+4*hi, col=q
  float mrow = -1e30f, lsum = 0.f;

  for (int j = 0; j <= qb; ++j) {
    if (!((qb - j) < 16 || ((j + 1) & 7) == 0)) continue;
    const bool diag = (j == qb);
    const bool short_blk = diag && (half == 0);  // k-subtile 1 fully masked

    f32x16 st[2] = {};
    {
      const unsigned short* kb = Kh + ((size_t)(g * SEQ + j * 64 + l31)) * HD + hi * 8;
#pragma unroll
      for (int kk = 0; kk < 8; ++kk)
        st[0] = __builtin_amdgcn_mfma_f32_32x32x16_bf16(
            *reinterpret_cast<const bf16x8*>(kb + kk * 16), qf[kk], st[0], 0, 0, 0);
    }
    if (!short_blk) {
      const unsigned short* kb = Kh + ((size_t)(g * SEQ + j * 64 + 32 + l31)) * HD + hi * 8;
#pragma unroll
      for (int kk = 0; kk < 8; ++kk)
        st[1] = __builtin_amdgcn_mfma_f32_32x32x16_bf16(
            *reinterpret_cast<const bf16x8*>(kb + kk * 16), qf[kk], st[1], 0, 0, 0);
    }

    if (diag) {
      int qrel = half * 32 + l31;
#pragma unroll
      for (int kt = 0; kt < 2; ++kt)
#pragma unroll
        for (int r = 0; r < 16; ++r) {
          int krel = kt * 32 + (r & 3) + 8 * (r >> 2) + 4 * hi;
          if (krel > qrel) st[kt][r] = -1e30f;
        }
    }

    float t16[16];
#pragma unroll
    for (int r = 0; r < 16; ++r) t16[r] = fmaxf(st[0][r], st[1][r]);
#pragma unroll
    for (int sft = 8; sft >= 1; sft >>= 1)
#pragma unroll
      for (int r = 0; r < sft; ++r) t16[r] = fmaxf(t16[r], t16[r + sft]);
    float vm = xmax32(t16[0]);

    if (!__all(vm - mrow <= 8.0f)) {  // T13 defer-max
      float nm = fmaxf(mrow, vm);
      float corr = __builtin_amdgcn_exp2f(mrow - nm);
      lsum *= corr;
#pragma unroll
      for (int dt = 0; dt < 4; ++dt)
#pragma unroll
        for (int r = 0; r < 16; ++r) ot[dt][r] *= corr;
      mrow = nm;
    }

    float s4[4] = {0.f, 0.f, 0.f, 0.f};
#pragma unroll
    for (int kt = 0; kt < 2; ++kt)
#pragma unroll
      for (int r = 0; r < 16; ++r) {
        float p = __builtin_amdgcn_exp2f(st[kt][r] - mrow);
        st[kt][r] = p;
        s4[r & 3] += p;
      }
    lsum += xadd32((s4[0] + s4[1]) + (s4[2] + s4[3]));

    bf16x8 pb[4];  // T12: P^T B-frags in-register
#pragma unroll
    for (int s = 0; s < 4; ++s) {
      int kt = s >> 1, g0 = (s & 1) * 2, g1 = g0 + 1;
      unsigned int a0 = pk(st[kt][4 * g0 + 0], st[kt][4 * g0 + 1]);
      unsigned int a1 = pk(st[kt][4 * g0 + 2], st[kt][4 * g0 + 3]);
      unsigned int b0 = pk(st[kt][4 * g1 + 0], st[kt][4 * g1 + 1]);
      unsigned int b1 = pk(st[kt][4 * g1 + 2], st[kt][4 * g1 + 3]);
      pswap(a0, b0);
      pswap(a1, b1);
      union { unsigned int u[4]; bf16x8 v; } t;
      t.u[0] = a0; t.u[1] = a1; t.u[2] = b0; t.u[3] = b1;
      pb[s] = t.v;
    }

    const int smax = short_blk ? 2 : 4;
#pragma unroll
    for (int dt = 0; dt < 4; ++dt) {
      const unsigned short* vb =
          Vt + ((size_t)(g * HD + dt * 32 + l31)) * SEQ + j * 64 + hi * 8;
#pragma unroll
      for (int s = 0; s < 4; ++s)
        if (s < smax)
          ot[dt] = __builtin_amdgcn_mfma_f32_32x32x16_bf16(
              *reinterpret_cast<const bf16x8*>(vb + s * 16), pb[s], ot[dt], 0, 0, 0);
    }
  }

  float inv = 1.0f / lsum;
  const int swz = (l31 & 7) << 4;
#pragma unroll
  for (int dt = 0; dt < 4; ++dt)
#pragma unroll
    for (int gg = 0; gg < 4; ++gg) {
      unsigned int u0 = pk(ot[dt][4 * gg + 0] * inv, ot[dt][4 * gg + 1] * inv);
      unsigned int u1 = pk(ot[dt][4 * gg + 2] * inv, ot[dt][4 * gg + 3] * inv);
      int off = (dt * 64 + gg * 16 + hi * 8) ^ swz;
      *reinterpret_cast<uint2*>(W + l31 * 256 + off) = make_uint2(u0, u1);
    }
#pragma unroll
  for (int i = 0; i < 8; ++i) {
    int row = lane >> 1;
    int t = (lane & 1) * 8 + i;
    bf16x8 vv = *reinterpret_cast<const bf16x8*>(
        W + row * 256 + ((t * 16) ^ ((row & 7) << 4)));
    *reinterpret_cast<bf16x8*>(&ctx[(size_t)(Q0 + row) * HIDDEN + h * HD + t * 8]) = vv;
  }
}

extern "C" void kernel_launch(void* const* d_in, const int* in_sizes, int n_in,
                              void* d_out, int out_size, void* d_ws, size_t ws_size,
                              hipStream_t stream) {
  const float* hidden  = (const float*)d_in[0];
  const float* w_qkv   = (const float*)d_in[1];
  const float* b_qkv   = (const float*)d_in[2];
  const float* w_dense = (const float*)d_in[3];
  const float* b_dense = (const float*)d_in[4];
  float* out = (float*)d_out;

  char* p = (char*)d_ws;
  unsigned short* hid_bf  = (unsigned short*)p; p += (size_t)SEQ * HIDDEN * 2;
  unsigned short* wqkv_bf = (unsigned short*)p; p += (size_t)QKV_OUT * HIDDEN * 2;
  unsigned short* wd_bf   = (unsigned short*)p; p += (size_t)HIDDEN * HIDDEN * 2;
  float* qkv              = (float*)p;          p += (size_t)SEQ * QKV_OUT * 4;
  unsigned short* Qb      = (unsigned short*)p; p += (size_t)NH * SEQ * HD * 2;
  unsigned short* Kb      = (unsigned short*)p; p += (size_t)NKV * SEQ * HD * 2;
  unsigned short* Vt      = (unsigned short*)p; p += (size_t)NKV * HD * SEQ * 2;
  float* ct               = (float*)p;          p += (size_t)SEQ * 64 * 4;
  float* st               = (float*)p;          p += (size_t)SEQ * 64 * 4;
  unsigned short* ctx = hid_bf;  // hidden_bf16 dead after QKV GEMM

  conv_bf16<<<(SEQ * HIDDEN) / 2048, 256, 0, stream>>>(hidden, hid_bf, SEQ * HIDDEN);
  conv_bf16<<<(QKV_OUT * HIDDEN) / 2048, 256, 0, stream>>>(w_qkv, wqkv_bf, QKV_OUT * HIDDEN);
  conv_bf16<<<(HIDDEN * HIDDEN) / 2048, 256, 0, stream>>>(w_dense, wd_bf, HIDDEN * HIDDEN);
  build_tab<<<(SEQ * 64) / 256, 256, 0, stream>>>(ct, st);

  gemm8<256, 256, 2, 2><<<dim3((SEQ / 256) * (QKV_OUT / 256)), 512, 0, stream>>>(
      hid_bf, wqkv_bf, b_qkv, qkv, SEQ, QKV_OUT, HIDDEN);
  rope_split<<<(SEQ * 48 * 128) / 256, 256, 0, stream>>>(qkv, ct, st, Qb, Kb, Vt);
  attn32<<<dim3(NKV, SEQ / 32), 256, 0, stream>>>(Qb, Kb, Vt, ctx);
  gemm8<128, 256, 1, 2><<<dim3((SEQ / 128) * (HIDDEN / 256)), 512, 0, stream>>>(
      ctx, wd_bf, b_dense, out, SEQ, HIDDEN, HIDDEN);
}

// Round 8
// 302.537 us; speedup vs baseline: 1.7601x; 1.2907x over previous
//
#include <hip/hip_runtime.h>
#include <hip/hip_bf16.h>

#define SEQ 2048
#define HIDDEN 4096
#define NH 32
#define NKV 8
#define HD 128
#define QKV_OUT 6144   // (32 + 2*8) * 128
// Q is pre-scaled by SM_SCALE*log2(e) so softmax uses exp2 directly.
#define QSCALE (0.0078125f * 1.4426950408889634f)

typedef __attribute__((ext_vector_type(8))) short bf16x8;
typedef __attribute__((ext_vector_type(4))) float f32x4;
typedef __attribute__((ext_vector_type(16))) float f32x16;

__device__ inline unsigned short f32_bf16(float f) {
  union { float f; unsigned int u; } v; v.f = f;
  unsigned int r = v.u + 0x7FFFu + ((v.u >> 16) & 1u);
  return (unsigned short)(r >> 16);
}
__device__ inline unsigned int pk(float a, float b) {
  union { __hip_bfloat162 h; unsigned int u; } t;
  t.h = __float22bfloat162_rn(make_float2(a, b));
  return t.u;
}
__device__ inline void pswap(unsigned int &a, unsigned int &b) {
  auto r = __builtin_amdgcn_permlane32_swap((int)a, (int)b, false, false);
  a = (unsigned int)r[0]; b = (unsigned int)r[1];
}
__device__ inline float xmax32(float v) {
  int x = __builtin_bit_cast(int, v);
  auto r = __builtin_amdgcn_permlane32_swap(x, x, false, false);
  return fmaxf(__builtin_bit_cast(float, (int)r[0]), __builtin_bit_cast(float, (int)r[1]));
}
__device__ inline float xadd32(float v) {
  int x = __builtin_bit_cast(int, v);
  auto r = __builtin_amdgcn_permlane32_swap(x, x, false, false);
  return __builtin_bit_cast(float, (int)r[0]) + __builtin_bit_cast(float, (int)r[1]);
}

// ---------------- fp32 -> bf16 bulk conversion ----------------
__global__ __launch_bounds__(256) void conv_bf16(const float* __restrict__ in,
                                                 unsigned short* __restrict__ out,
                                                 int n) {
  int i = (blockIdx.x * 256 + threadIdx.x) * 8;
  if (i + 8 > n) return;
  float4 a = *reinterpret_cast<const float4*>(in + i);
  float4 b = *reinterpret_cast<const float4*>(in + i + 4);
  unsigned short t[8];
  t[0] = f32_bf16(a.x); t[1] = f32_bf16(a.y); t[2] = f32_bf16(a.z); t[3] = f32_bf16(a.w);
  t[4] = f32_bf16(b.x); t[5] = f32_bf16(b.y); t[6] = f32_bf16(b.z); t[7] = f32_bf16(b.w);
  *reinterpret_cast<uint4*>(out + i) = *reinterpret_cast<uint4*>(t);
}

// ---------------- RoPE cos/sin tables [SEQ][64] ----------------
__global__ __launch_bounds__(256) void build_tab(float* __restrict__ ct,
                                                 float* __restrict__ st) {
  int idx = blockIdx.x * 256 + threadIdx.x;  // SEQ*64
  int s = idx >> 6, d = idx & 63;
  float inv = powf(1.0e6f, -(float)d * (1.0f / 64.0f));
  float f = (float)s * inv;
  ct[idx] = cosf(f);
  st[idx] = sinf(f);
}

// ---------------- 4-phase K-sliced GEMM: C[M,N] = A[M,K]*B[N,K]^T + bias ----
// (unchanged from R4 — passed validation repeatedly)
template <int BM, int BN, int LA, int LB>
__global__ __launch_bounds__(512, 2) void gemm8(const unsigned short* __restrict__ A,
                                                const unsigned short* __restrict__ B,
                                                const float* __restrict__ bias,
                                                float* __restrict__ C,
                                                int M, int N, int K) {
  constexpr int MREP = BM / 32;
  constexpr int NREP = BN / 64;
  constexpr int HALF = (BM + BN) * 64;
  constexpr int BUF = HALF * 2;
  constexpr int LP = LA + LB;
  __shared__ __align__(16) char Lds[BUF * 2];

  const int tid = threadIdx.x;
  const int wave = tid >> 6, lane = tid & 63;
  const int wr = wave >> 2, wc = wave & 3;
  const int lrow = lane & 15, lgrp = lane >> 4;

  const int nwg = gridDim.x;
  const int wg0 = blockIdx.x;
  const int wg = (wg0 & 7) * (nwg >> 3) + (wg0 >> 3);
  const int ntx = N / BN;
  const int bm = (wg / ntx) * BM, bn = (wg % ntx) * BN;

  const int srow = lane >> 2;
  const int scol = ((lane & 3) ^ ((lane >= 32) ? 2 : 0)) * 8;
  const unsigned short* gA = A + (size_t)(bm + wave * (BM / 8) + srow) * K + scol;
  const unsigned short* gB = B + (size_t)(bn + wave * (BN / 8) + srow) * K + scol;
  const int ldsAw = wave * (BM / 8) * 64;
  const int ldsBw = BM * 64 + wave * (BN / 8) * 64;

  auto stage = [&](int bufb, int h, int k0) {
#pragma unroll
    for (int i = 0; i < LA; ++i)
      __builtin_amdgcn_global_load_lds(
          (const __attribute__((address_space(1))) unsigned int*)(gA + (size_t)(i * 16) * K + k0 + h * 32),
          (__attribute__((address_space(3))) unsigned int*)(Lds + bufb + h * HALF + ldsAw + i * 1024),
          16, 0, 0);
#pragma unroll
    for (int i = 0; i < LB; ++i)
      __builtin_amdgcn_global_load_lds(
          (const __attribute__((address_space(1))) unsigned int*)(gB + (size_t)(i * 16) * K + k0 + h * 32),
          (__attribute__((address_space(3))) unsigned int*)(Lds + bufb + h * HALF + ldsBw + i * 1024),
          16, 0, 0);
  };

  const int flip = ((lrow >> 3) & 1) << 5;
  const int aoff = (wr * (BM / 2) + lrow) * 64 + ((lgrp * 16) ^ flip);
  const int boff = BM * 64 + (wc * (BN / 4) + lrow) * 64 + ((lgrp * 16) ^ flip);

  f32x4 acc[MREP][NREP] = {};

  auto phase = [&](int cur, int h) {
    const char* base = Lds + cur + h * HALF;
    bf16x8 af[MREP], bfr[NREP];
#pragma unroll
    for (int m = 0; m < MREP; ++m)
      af[m] = *reinterpret_cast<const bf16x8*>(base + aoff + m * 1024);
#pragma unroll
    for (int n = 0; n < NREP; ++n)
      bfr[n] = *reinterpret_cast<const bf16x8*>(base + boff + n * 1024);
    __builtin_amdgcn_s_setprio(1);
#pragma unroll
    for (int m = 0; m < MREP; ++m)
#pragma unroll
      for (int n = 0; n < NREP; ++n)
        acc[m][n] = __builtin_amdgcn_mfma_f32_16x16x32_bf16(af[m], bfr[n], acc[m][n], 0, 0, 0);
    __builtin_amdgcn_s_setprio(0);
  };

  const int nt = K / 64;
  stage(0, 0, 0);
  stage(0, 1, 0);
  for (int t = 0; t < nt - 1; ++t) {
    const int cur = (t & 1) ? BUF : 0;
    const int nxt = cur ^ BUF;
    const int k1 = (t + 1) * 64;
#pragma unroll
    for (int h = 0; h < 2; ++h) {
      stage(nxt, h, k1);
      if constexpr (LP == 4) asm volatile("s_waitcnt vmcnt(8)" ::: "memory");
      else                   asm volatile("s_waitcnt vmcnt(6)" ::: "memory");
      __builtin_amdgcn_s_barrier();
      asm volatile("" ::: "memory");
      phase(cur, h);
    }
  }
  {
    const int cur = ((nt - 1) & 1) ? BUF : 0;
    if constexpr (LP == 4) asm volatile("s_waitcnt vmcnt(4)" ::: "memory");
    else                   asm volatile("s_waitcnt vmcnt(3)" ::: "memory");
    __builtin_amdgcn_s_barrier();
    asm volatile("" ::: "memory");
    phase(cur, 0);
    asm volatile("s_waitcnt vmcnt(0)" ::: "memory");
    __builtin_amdgcn_s_barrier();
    asm volatile("" ::: "memory");
    phase(cur, 1);
  }

#pragma unroll
  for (int n = 0; n < NREP; ++n) {
    int col = bn + wc * (BN / 4) + n * 16 + lrow;
    float bv = bias[col];
#pragma unroll
    for (int m = 0; m < MREP; ++m)
#pragma unroll
      for (int r = 0; r < 4; ++r) {
        int row = bm + wr * (BM / 2) + m * 16 + lgrp * 4 + r;
        C[(size_t)row * N + col] = acc[m][n][r] + bv;
      }
  }
}

// ---------------- RoPE + split into Q / K / V^T (bf16) ----------------
__global__ __launch_bounds__(256) void rope_split(const float* __restrict__ qkv,
                                                  const float* __restrict__ ct,
                                                  const float* __restrict__ st,
                                                  unsigned short* __restrict__ Q,
                                                  unsigned short* __restrict__ Kh,
                                                  unsigned short* __restrict__ Vt) {
  int idx = blockIdx.x * 256 + threadIdx.x;  // SEQ*48*128
  int d = idx & 127;
  int t = idx >> 7;
  int head = t % 48;
  int s = t / 48;
  int gg = head / 6, slot = head - gg * 6;
  const float* base = qkv + (size_t)s * QKV_OUT + gg * 768 + slot * 128;
  float x = base[d];
  if (slot == 5) {
    Vt[((size_t)gg * HD + d) * SEQ + s] = f32_bf16(x);
  } else {
    int dm = d & 63;
    float c = ct[s * 64 + dm], sn = st[s * 64 + dm];
    float rot = (d < 64) ? -base[d + 64] : base[d - 64];
    float val = x * c + rot * sn;
    if (slot < 4)
      Q[((size_t)(gg * 4 + slot) * SEQ + s) * HD + d] = f32_bf16(val * QSCALE);
    else
      Kh[((size_t)gg * SEQ + s) * HD + d] = f32_bf16(val);
  }
}

// next valid blocksparse j >= x for this qb (uniform across block), -1 if none.
// Valid j: (qb - j < 16) OR ((j+1) % 8 == 0). When outside the local window,
// the next candidate is min(next vertical, window start qb-15)  [R5/R6 bug:
// the qb-15 candidate was missing, silently skipping local blocks for
// qb%8 in 1..6].
__device__ inline int nextj(int x, int qb) {
  if (x > qb) return -1;
  if (qb - x < 16) return x;          // inside local window: every block valid
  int v = (x & ~7) + 7;               // next vertical column ((j+1)%8==0)
  int w = qb - 15;                    // local window start (> x here)
  return v < w ? v : w;
}

// ---------------- blocksparse flash attention, LDS-staged K/V ----------------
// T3-minimum 2-phase schedule (m248v2 pattern): stage(nxt) -> compute(cur) ->
// vmcnt(0) -> barrier, one barrier per j-block, sched_barrier(0) fences
// (rule #18) so nothing crosses the waitcnt/barrier pair.
__global__ __launch_bounds__(256, 2) void attn32(const unsigned short* __restrict__ Q,
                                                 const unsigned short* __restrict__ Kh,
                                                 const unsigned short* __restrict__ Vt,
                                                 unsigned short* __restrict__ ctx) {
  const int g = blockIdx.x;
  const int y = (int)gridDim.y - 1 - (int)blockIdx.y;  // big qb first
  const int qb = y >> 1, half = y & 1;
  const int Q0 = y * 32;
  const int tid = threadIdx.x;
  const int wave = tid >> 6;
  const int h = g * 4 + wave;
  const int lane = tid & 63;
  const int l31 = lane & 31, hi = lane >> 5;

  // [2 bufs][ K 16KB | V 16KB ]; epilogue reuses first 32KB after sync
  __shared__ __align__(16) char Lds[65536];

  // stage one j-block: K rows (256B) and V^T rows (128B), granule-XOR source
  auto stage = [&](int bufb, int j) {
#pragma unroll
    for (int i = 0; i < 4; ++i) {
      int row = i * 16 + (tid >> 4);
      const unsigned short* src =
          Kh + ((size_t)(g * SEQ + j * 64 + row)) * HD + ((tid & 15) ^ (row & 15)) * 8;
      __builtin_amdgcn_global_load_lds(
          (const __attribute__((address_space(1))) unsigned int*)src,
          (__attribute__((address_space(3))) unsigned int*)(Lds + bufb + i * 4096 + (tid >> 6) * 1024),
          16, 0, 0);
    }
#pragma unroll
    for (int i = 0; i < 4; ++i) {
      int row = i * 32 + (tid >> 3);
      const unsigned short* src =
          Vt + ((size_t)(g * HD + row)) * SEQ + j * 64 + ((tid & 7) ^ (row & 7)) * 8;
      __builtin_amdgcn_global_load_lds(
          (const __attribute__((address_space(1))) unsigned int*)src,
          (__attribute__((address_space(3))) unsigned int*)(Lds + bufb + 16384 + i * 4096 + (tid >> 6) * 1024),
          16, 0, 0);
    }
  };

  bf16x8 qf[8];  // B-operand: col=q=l31, hd = kk*16 + hi*8 + e
  const unsigned short* qbase = Q + ((size_t)h * SEQ + Q0 + l31) * HD;
#pragma unroll
  for (int kk = 0; kk < 8; ++kk)
    qf[kk] = *reinterpret_cast<const bf16x8*>(qbase + kk * 16 + hi * 8);

  f32x16 ot[4] = {};  // O^T: d = dt*32 + (r&3)+8*(r>>2)+4*hi, col=q
  float mrow = -1e30f, lsum = 0.f;

  const int kswz = l31 & 15;  // K granule XOR (row&15 == l31&15)
  const int vswz = l31 & 7;   // V granule XOR (row&7  == l31&7)

  int j = nextj(0, qb);
  int cur = 0;
  stage(0, j);
  asm volatile("s_waitcnt vmcnt(0)" ::: "memory");
  __builtin_amdgcn_sched_barrier(0);
  __builtin_amdgcn_s_barrier();
  __builtin_amdgcn_sched_barrier(0);

  while (true) {
    const int jn = (j < qb) ? nextj(j + 1, qb) : -1;
    if (jn >= 0) stage(cur ^ 32768, jn);  // prefetch next block (uniform branch)

    const char* kb = Lds + cur;
    const char* vb = Lds + cur + 16384;
    const bool diag = (j == qb);
    const bool short_blk = diag && (half == 0);  // k-subtile 1 fully masked

    // S^T = K * Q^T (two 32-row k-subtiles)
    f32x16 st[2] = {};
    __builtin_amdgcn_s_setprio(1);
#pragma unroll
    for (int kk = 0; kk < 8; ++kk) {
      bf16x8 k0 = *reinterpret_cast<const bf16x8*>(
          kb + (size_t)l31 * 256 + (((2 * kk + hi) ^ kswz) * 16));
      st[0] = __builtin_amdgcn_mfma_f32_32x32x16_bf16(k0, qf[kk], st[0], 0, 0, 0);
      if (!short_blk) {
        bf16x8 k1 = *reinterpret_cast<const bf16x8*>(
            kb + (size_t)(32 + l31) * 256 + (((2 * kk + hi) ^ kswz) * 16));
        st[1] = __builtin_amdgcn_mfma_f32_32x32x16_bf16(k1, qf[kk], st[1], 0, 0, 0);
      }
    }
    __builtin_amdgcn_s_setprio(0);

    if (diag) {
      int qrel = half * 32 + l31;
#pragma unroll
      for (int kt = 0; kt < 2; ++kt)
#pragma unroll
        for (int r = 0; r < 16; ++r) {
          int krel = kt * 32 + (r & 3) + 8 * (r >> 2) + 4 * hi;
          if (krel > qrel) st[kt][r] = -1e30f;
        }
    }

    float t16[16];
#pragma unroll
    for (int r = 0; r < 16; ++r) t16[r] = fmaxf(st[0][r], st[1][r]);
#pragma unroll
    for (int sft = 8; sft >= 1; sft >>= 1)
#pragma unroll
      for (int r = 0; r < sft; ++r) t16[r] = fmaxf(t16[r], t16[r + sft]);
    float vm = xmax32(t16[0]);

    if (!__all(vm - mrow <= 8.0f)) {  // T13 defer-max
      float nm = fmaxf(mrow, vm);
      float corr = __builtin_amdgcn_exp2f(mrow - nm);
      lsum *= corr;
#pragma unroll
      for (int dt = 0; dt < 4; ++dt)
#pragma unroll
        for (int r = 0; r < 16; ++r) ot[dt][r] *= corr;
      mrow = nm;
    }

    float s4[4] = {0.f, 0.f, 0.f, 0.f};
#pragma unroll
    for (int kt = 0; kt < 2; ++kt)
#pragma unroll
      for (int r = 0; r < 16; ++r) {
        float p = __builtin_amdgcn_exp2f(st[kt][r] - mrow);
        st[kt][r] = p;
        s4[r & 3] += p;
      }
    lsum += xadd32((s4[0] + s4[1]) + (s4[2] + s4[3]));

    bf16x8 pb[4];  // T12: P^T B-frags in-register
#pragma unroll
    for (int s = 0; s < 4; ++s) {
      int kt = s >> 1, g0 = (s & 1) * 2, g1 = g0 + 1;
      unsigned int a0 = pk(st[kt][4 * g0 + 0], st[kt][4 * g0 + 1]);
      unsigned int a1 = pk(st[kt][4 * g0 + 2], st[kt][4 * g0 + 3]);
      unsigned int b0 = pk(st[kt][4 * g1 + 0], st[kt][4 * g1 + 1]);
      unsigned int b1 = pk(st[kt][4 * g1 + 2], st[kt][4 * g1 + 3]);
      pswap(a0, b0);
      pswap(a1, b1);
      union { unsigned int u[4]; bf16x8 v; } t;
      t.u[0] = a0; t.u[1] = a1; t.u[2] = b0; t.u[3] = b1;
      pb[s] = t.v;
    }

    const int smax = short_blk ? 2 : 4;
    __builtin_amdgcn_s_setprio(1);
#pragma unroll
    for (int dt = 0; dt < 4; ++dt) {
      const char* vrow = vb + (size_t)(dt * 32 + l31) * 128;
#pragma unroll
      for (int s = 0; s < 4; ++s)
        if (s < smax)
          ot[dt] = __builtin_amdgcn_mfma_f32_32x32x16_bf16(
              *reinterpret_cast<const bf16x8*>(vrow + (((2 * s + hi) ^ vswz) * 16)),
              pb[s], ot[dt], 0, 0, 0);
    }
    __builtin_amdgcn_s_setprio(0);

    if (jn < 0) break;
    // drain prefetch + join waves: nxt fully staged, cur safe to overwrite
    asm volatile("s_waitcnt vmcnt(0)" ::: "memory");
    __builtin_amdgcn_sched_barrier(0);
    __builtin_amdgcn_s_barrier();
    __builtin_amdgcn_sched_barrier(0);
    j = jn;
    cur ^= 32768;
  }

  // epilogue: normalize + transpose O^T via XOR-swizzled LDS, 16B stores
  __syncthreads();  // full fence before reusing staging LDS
  char* W = Lds + wave * 8192;
  float inv = 1.0f / lsum;
  const int swz = (l31 & 7) << 4;
#pragma unroll
  for (int dt = 0; dt < 4; ++dt)
#pragma unroll
    for (int gg = 0; gg < 4; ++gg) {
      unsigned int u0 = pk(ot[dt][4 * gg + 0] * inv, ot[dt][4 * gg + 1] * inv);
      unsigned int u1 = pk(ot[dt][4 * gg + 2] * inv, ot[dt][4 * gg + 3] * inv);
      int off = (dt * 64 + gg * 16 + hi * 8) ^ swz;
      *reinterpret_cast<uint2*>(W + l31 * 256 + off) = make_uint2(u0, u1);
    }
#pragma unroll
  for (int i = 0; i < 8; ++i) {
    int row = lane >> 1;
    int t = (lane & 1) * 8 + i;
    bf16x8 vv = *reinterpret_cast<const bf16x8*>(
        W + row * 256 + ((t * 16) ^ ((row & 7) << 4)));
    *reinterpret_cast<bf16x8*>(&ctx[(size_t)(Q0 + row) * HIDDEN + h * HD + t * 8]) = vv;
  }
}

extern "C" void kernel_launch(void* const* d_in, const int* in_sizes, int n_in,
                              void* d_out, int out_size, void* d_ws, size_t ws_size,
                              hipStream_t stream) {
  const float* hidden  = (const float*)d_in[0];
  const float* w_qkv   = (const float*)d_in[1];
  const float* b_qkv   = (const float*)d_in[2];
  const float* w_dense = (const float*)d_in[3];
  const float* b_dense = (const float*)d_in[4];
  float* out = (float*)d_out;

  char* p = (char*)d_ws;
  unsigned short* hid_bf  = (unsigned short*)p; p += (size_t)SEQ * HIDDEN * 2;
  unsigned short* wqkv_bf = (unsigned short*)p; p += (size_t)QKV_OUT * HIDDEN * 2;
  unsigned short* wd_bf   = (unsigned short*)p; p += (size_t)HIDDEN * HIDDEN * 2;
  float* qkv              = (float*)p;          p += (size_t)SEQ * QKV_OUT * 4;
  unsigned short* Qb      = (unsigned short*)p; p += (size_t)NH * SEQ * HD * 2;
  unsigned short* Kb      = (unsigned short*)p; p += (size_t)NKV * SEQ * HD * 2;
  unsigned short* Vt      = (unsigned short*)p; p += (size_t)NKV * HD * SEQ * 2;
  float* ct               = (float*)p;          p += (size_t)SEQ * 64 * 4;
  float* st               = (float*)p;          p += (size_t)SEQ * 64 * 4;
  unsigned short* ctx = hid_bf;  // hidden_bf16 dead after QKV GEMM

  conv_bf16<<<(SEQ * HIDDEN) / 2048, 256, 0, stream>>>(hidden, hid_bf, SEQ * HIDDEN);
  conv_bf16<<<(QKV_OUT * HIDDEN) / 2048, 256, 0, stream>>>(w_qkv, wqkv_bf, QKV_OUT * HIDDEN);
  conv_bf16<<<(HIDDEN * HIDDEN) / 2048, 256, 0, stream>>>(w_dense, wd_bf, HIDDEN * HIDDEN);
  build_tab<<<(SEQ * 64) / 256, 256, 0, stream>>>(ct, st);

  gemm8<256, 256, 2, 2><<<dim3((SEQ / 256) * (QKV_OUT / 256)), 512, 0, stream>>>(
      hid_bf, wqkv_bf, b_qkv, qkv, SEQ, QKV_OUT, HIDDEN);
  rope_split<<<(SEQ * 48 * 128) / 256, 256, 0, stream>>>(qkv, ct, st, Qb, Kb, Vt);
  attn32<<<dim3(NKV, SEQ / 32), 256, 0, stream>>>(Qb, Kb, Vt, ctx);
  gemm8<128, 256, 1, 2><<<dim3((SEQ / 128) * (HIDDEN / 256)), 512, 0, stream>>>(
      ctx, wd_bf, b_dense, out, SEQ, HIDDEN, HIDDEN);
}

// Round 9
// 287.557 us; speedup vs baseline: 1.8518x; 1.0521x over previous
//
#include <hip/hip_runtime.h>
#include <hip/hip_bf16.h>

#define SEQ 2048
#define HIDDEN 4096
#define NH 32
#define NKV 8
#define HD 128
#define QKV_OUT 6144   // (32 + 2*8) * 128
// Q is pre-scaled by SM_SCALE*log2(e) so softmax uses exp2 directly.
#define QSCALE (0.0078125f * 1.4426950408889634f)

typedef __attribute__((ext_vector_type(8))) short bf16x8;
typedef __attribute__((ext_vector_type(4))) float f32x4;
typedef __attribute__((ext_vector_type(16))) float f32x16;

__device__ inline unsigned short f32_bf16(float f) {
  union { float f; unsigned int u; } v; v.f = f;
  unsigned int r = v.u + 0x7FFFu + ((v.u >> 16) & 1u);
  return (unsigned short)(r >> 16);
}
__device__ inline float bf16_f32(unsigned short u) {
  union { unsigned int u; float f; } v; v.u = (unsigned int)u << 16;
  return v.f;
}
__device__ inline unsigned int pk(float a, float b) {
  union { __hip_bfloat162 h; unsigned int u; } t;
  t.h = __float22bfloat162_rn(make_float2(a, b));
  return t.u;
}
__device__ inline void pswap(unsigned int &a, unsigned int &b) {
  auto r = __builtin_amdgcn_permlane32_swap((int)a, (int)b, false, false);
  a = (unsigned int)r[0]; b = (unsigned int)r[1];
}
__device__ inline float xmax32(float v) {
  int x = __builtin_bit_cast(int, v);
  auto r = __builtin_amdgcn_permlane32_swap(x, x, false, false);
  return fmaxf(__builtin_bit_cast(float, (int)r[0]), __builtin_bit_cast(float, (int)r[1]));
}
__device__ inline float xadd32(float v) {
  int x = __builtin_bit_cast(int, v);
  auto r = __builtin_amdgcn_permlane32_swap(x, x, false, false);
  return __builtin_bit_cast(float, (int)r[0]) + __builtin_bit_cast(float, (int)r[1]);
}

// ---------------- fp32 -> bf16 bulk conversion ----------------
__global__ __launch_bounds__(256) void conv_bf16(const float* __restrict__ in,
                                                 unsigned short* __restrict__ out,
                                                 int n) {
  int i = (blockIdx.x * 256 + threadIdx.x) * 8;
  if (i + 8 > n) return;
  float4 a = *reinterpret_cast<const float4*>(in + i);
  float4 b = *reinterpret_cast<const float4*>(in + i + 4);
  unsigned short t[8];
  t[0] = f32_bf16(a.x); t[1] = f32_bf16(a.y); t[2] = f32_bf16(a.z); t[3] = f32_bf16(a.w);
  t[4] = f32_bf16(b.x); t[5] = f32_bf16(b.y); t[6] = f32_bf16(b.z); t[7] = f32_bf16(b.w);
  *reinterpret_cast<uint4*>(out + i) = *reinterpret_cast<uint4*>(t);
}

// ---------------- RoPE cos/sin tables [SEQ][64] ----------------
__global__ __launch_bounds__(256) void build_tab(float* __restrict__ ct,
                                                 float* __restrict__ st) {
  int idx = blockIdx.x * 256 + threadIdx.x;  // SEQ*64
  int s = idx >> 6, d = idx & 63;
  float inv = powf(1.0e6f, -(float)d * (1.0f / 64.0f));
  float f = (float)s * inv;
  ct[idx] = cosf(f);
  st[idx] = sinf(f);
}

// ---------------- K-sliced GEMM, quadrant-split phases -----------------------
// C[M,N] = A[M,K]*B[N,K]^T + bias. 512 threads = 8 waves (2M x 4N).
// Same stage/vmcnt/barrier skeleton as the R8-passing kernel; each K-slice's
// compute is split into 2 sub-phases (m201 pattern) with a uniform mid-barrier.
// 2D XCD chunking (CR x CC blocks per XCD). OBF: write bf16 output.
template <int BM, int BN, int LA, int LB, int CR, int CC, bool OBF>
__global__ __launch_bounds__(512, 2) void gemm8(const unsigned short* __restrict__ A,
                                                const unsigned short* __restrict__ B,
                                                const float* __restrict__ bias,
                                                void* __restrict__ Cp,
                                                int M, int N, int K) {
  constexpr int MREP = BM / 32;
  constexpr int NREP = BN / 64;
  constexpr int MH = MREP / 2;
  constexpr int HALF = (BM + BN) * 64;
  constexpr int BUF = HALF * 2;
  constexpr int LP = LA + LB;
  __shared__ __align__(16) char Lds[BUF * 2];

  const int tid = threadIdx.x;
  const int wave = tid >> 6, lane = tid & 63;
  const int wr = wave >> 2, wc = wave & 3;
  const int lrow = lane & 15, lgrp = lane >> 4;

  // 2D XCD chunk: xcd = wg0 & 7 owns a CR x CC rectangle of tiles.
  const int ntx = N / BN;
  const int wg0 = blockIdx.x;
  const int xcd = wg0 & 7, w = wg0 >> 3;
  constexpr int CPB = 0;  // placeholder
  const int cpb = ntx / CC;              // col-chunks per band
  const int band = xcd / cpb, colc = xcd % cpb;
  const int bmi = band * CR + w / CC;
  const int bni = colc * CC + w % CC;
  const int bm = bmi * BM, bn = bni * BN;

  const int srow = lane >> 2;
  const int scol = ((lane & 3) ^ ((lane >= 32) ? 2 : 0)) * 8;
  const unsigned short* gA = A + (size_t)(bm + wave * (BM / 8) + srow) * K + scol;
  const unsigned short* gB = B + (size_t)(bn + wave * (BN / 8) + srow) * K + scol;
  const int ldsAw = wave * (BM / 8) * 64;
  const int ldsBw = BM * 64 + wave * (BN / 8) * 64;

  auto stage = [&](int bufb, int h, int k0) {
#pragma unroll
    for (int i = 0; i < LA; ++i)
      __builtin_amdgcn_global_load_lds(
          (const __attribute__((address_space(1))) unsigned int*)(gA + (size_t)(i * 16) * K + k0 + h * 32),
          (__attribute__((address_space(3))) unsigned int*)(Lds + bufb + h * HALF + ldsAw + i * 1024),
          16, 0, 0);
#pragma unroll
    for (int i = 0; i < LB; ++i)
      __builtin_amdgcn_global_load_lds(
          (const __attribute__((address_space(1))) unsigned int*)(gB + (size_t)(i * 16) * K + k0 + h * 32),
          (__attribute__((address_space(3))) unsigned int*)(Lds + bufb + h * HALF + ldsBw + i * 1024),
          16, 0, 0);
  };

  const int flip = ((lrow >> 3) & 1) << 5;
  const int aoff = (wr * (BM / 2) + lrow) * 64 + ((lgrp * 16) ^ flip);
  const int boff = BM * 64 + (wc * (BN / 4) + lrow) * 64 + ((lgrp * 16) ^ flip);

  f32x4 acc[MREP][NREP] = {};

  // quadrant-split compute of one K-slice (all reads from `base` = cur buffer)
  auto phase = [&](int cur, int h) {
    const char* base = Lds + cur + h * HALF;
    bf16x8 af[MREP], bfr[NREP];
#pragma unroll
    for (int m = 0; m < MH; ++m)
      af[m] = *reinterpret_cast<const bf16x8*>(base + aoff + m * 1024);
#pragma unroll
    for (int n = 0; n < NREP; ++n)
      bfr[n] = *reinterpret_cast<const bf16x8*>(base + boff + n * 1024);
    asm volatile("s_waitcnt lgkmcnt(0)" ::: "memory");
    __builtin_amdgcn_sched_barrier(0);
    __builtin_amdgcn_s_setprio(1);
#pragma unroll
    for (int m = 0; m < MH; ++m)
#pragma unroll
      for (int n = 0; n < NREP; ++n)
        acc[m][n] = __builtin_amdgcn_mfma_f32_16x16x32_bf16(af[m], bfr[n], acc[m][n], 0, 0, 0);
    __builtin_amdgcn_s_setprio(0);
    __builtin_amdgcn_sched_barrier(0);
#pragma unroll
    for (int m = MH; m < MREP; ++m)
      af[m] = *reinterpret_cast<const bf16x8*>(base + aoff + m * 1024);
    __builtin_amdgcn_s_barrier();           // uniform mid-barrier (m201 phase split)
    asm volatile("s_waitcnt lgkmcnt(0)" ::: "memory");
    __builtin_amdgcn_sched_barrier(0);
    __builtin_amdgcn_s_setprio(1);
#pragma unroll
    for (int m = MH; m < MREP; ++m)
#pragma unroll
      for (int n = 0; n < NREP; ++n)
        acc[m][n] = __builtin_amdgcn_mfma_f32_16x16x32_bf16(af[m], bfr[n], acc[m][n], 0, 0, 0);
    __builtin_amdgcn_s_setprio(0);
  };

  const int nt = K / 64;
  stage(0, 0, 0);
  stage(0, 1, 0);
  for (int t = 0; t < nt - 1; ++t) {
    const int cur = (t & 1) ? BUF : 0;
    const int nxt = cur ^ BUF;
    const int k1 = (t + 1) * 64;
#pragma unroll
    for (int h = 0; h < 2; ++h) {
      stage(nxt, h, k1);
      if constexpr (LP == 4) asm volatile("s_waitcnt vmcnt(8)" ::: "memory");
      else                   asm volatile("s_waitcnt vmcnt(6)" ::: "memory");
      __builtin_amdgcn_s_barrier();
      asm volatile("" ::: "memory");
      phase(cur, h);
    }
  }
  {
    const int cur = ((nt - 1) & 1) ? BUF : 0;
    if constexpr (LP == 4) asm volatile("s_waitcnt vmcnt(4)" ::: "memory");
    else                   asm volatile("s_waitcnt vmcnt(3)" ::: "memory");
    __builtin_amdgcn_s_barrier();
    asm volatile("" ::: "memory");
    phase(cur, 0);
    asm volatile("s_waitcnt vmcnt(0)" ::: "memory");
    __builtin_amdgcn_s_barrier();
    asm volatile("" ::: "memory");
    phase(cur, 1);
  }

#pragma unroll
  for (int n = 0; n < NREP; ++n) {
    int col = bn + wc * (BN / 4) + n * 16 + lrow;
    float bv = bias[col];
#pragma unroll
    for (int m = 0; m < MREP; ++m)
#pragma unroll
      for (int r = 0; r < 4; ++r) {
        int row = bm + wr * (BM / 2) + m * 16 + lgrp * 4 + r;
        if constexpr (OBF)
          ((unsigned short*)Cp)[(size_t)row * N + col] = f32_bf16(acc[m][n][r] + bv);
        else
          ((float*)Cp)[(size_t)row * N + col] = acc[m][n][r] + bv;
      }
  }
}

// ---------------- RoPE + split (bf16 qkv input), vectorized ------------------
// qkvb bf16 [SEQ][8g][6slot][128]. Blocks [0,5120): Q/K slots (8 elems/thread,
// rope in fp32). Blocks [5120,6144): V transpose (8 s per thread, 16B stores).
__global__ __launch_bounds__(256) void rope_split(const unsigned short* __restrict__ qkvb,
                                                  const float* __restrict__ ct,
                                                  const float* __restrict__ st,
                                                  unsigned short* __restrict__ Q,
                                                  unsigned short* __restrict__ Kh,
                                                  unsigned short* __restrict__ Vt) {
  int b = blockIdx.x;
  if (b < 5120) {  // Q/K: t in [0, 1310720)
    int t = b * 256 + threadIdx.x;
    int d8 = (t & 15) * 8;
    int q = t >> 4;
    int s = q / 40;
    int slotg = q - s * 40;
    int g = slotg / 5, slot = slotg - g * 5;
    const unsigned short* base = qkvb + (size_t)s * QKV_OUT + g * 768 + slot * 128;
    bf16x8 x8 = *reinterpret_cast<const bf16x8*>(base + d8);
    bf16x8 r8 = *reinterpret_cast<const bf16x8*>(base + (d8 ^ 64));
    float4 c0 = *reinterpret_cast<const float4*>(ct + s * 64 + (d8 & 63));
    float4 c1 = *reinterpret_cast<const float4*>(ct + s * 64 + (d8 & 63) + 4);
    float4 s0 = *reinterpret_cast<const float4*>(st + s * 64 + (d8 & 63));
    float4 s1 = *reinterpret_cast<const float4*>(st + s * 64 + (d8 & 63) + 4);
    float cc[8] = {c0.x, c0.y, c0.z, c0.w, c1.x, c1.y, c1.z, c1.w};
    float ss[8] = {s0.x, s0.y, s0.z, s0.w, s1.x, s1.y, s1.z, s1.w};
    float sgn = (d8 < 64) ? -1.0f : 1.0f;
    float sc = (slot < 4) ? QSCALE : 1.0f;
    unsigned short o[8];
#pragma unroll
    for (int i = 0; i < 8; ++i) {
      float x = bf16_f32((unsigned short)x8[i]);
      float r = bf16_f32((unsigned short)r8[i]) * sgn;
      o[i] = f32_bf16((x * cc[i] + r * ss[i]) * sc);
    }
    unsigned short* dst = (slot < 4)
        ? Q + ((size_t)(g * 4 + slot) * SEQ + s) * HD + d8
        : Kh + ((size_t)g * SEQ + s) * HD + d8;
    *reinterpret_cast<uint4*>(dst) = *reinterpret_cast<uint4*>(o);
  } else {  // V: t2 in [0, 262144)
    int t2 = (b - 5120) * 256 + threadIdx.x;
    int d = t2 & 127;
    int rest = t2 >> 7;
    int g = rest & 7;
    int s0 = (rest >> 3) * 8;
    const unsigned short* src = qkvb + (size_t)s0 * QKV_OUT + g * 768 + 640 + d;
    unsigned short o[8];
#pragma unroll
    for (int i = 0; i < 8; ++i) o[i] = src[(size_t)i * QKV_OUT];
    *reinterpret_cast<uint4*>(&Vt[((size_t)g * HD + d) * SEQ + s0]) =
        *reinterpret_cast<uint4*>(o);
  }
}

// next valid blocksparse j >= x for this qb (uniform across block), -1 if none.
__device__ inline int nextj(int x, int qb) {
  if (x > qb) return -1;
  if (qb - x < 16) return x;          // inside local window: every block valid
  int v = (x & ~7) + 7;               // next vertical column ((j+1)%8==0)
  int w = qb - 15;                    // local window start (> x here)
  return v < w ? v : w;
}

// ---------------- blocksparse flash attention, LDS-staged K/V ----------------
// (unchanged from R8-passing version)
__global__ __launch_bounds__(256, 2) void attn32(const unsigned short* __restrict__ Q,
                                                 const unsigned short* __restrict__ Kh,
                                                 const unsigned short* __restrict__ Vt,
                                                 unsigned short* __restrict__ ctx) {
  const int g = blockIdx.x;
  const int y = (int)gridDim.y - 1 - (int)blockIdx.y;  // big qb first
  const int qb = y >> 1, half = y & 1;
  const int Q0 = y * 32;
  const int tid = threadIdx.x;
  const int wave = tid >> 6;
  const int h = g * 4 + wave;
  const int lane = tid & 63;
  const int l31 = lane & 31, hi = lane >> 5;

  __shared__ __align__(16) char Lds[65536];

  auto stage = [&](int bufb, int j) {
#pragma unroll
    for (int i = 0; i < 4; ++i) {
      int row = i * 16 + (tid >> 4);
      const unsigned short* src =
          Kh + ((size_t)(g * SEQ + j * 64 + row)) * HD + ((tid & 15) ^ (row & 15)) * 8;
      __builtin_amdgcn_global_load_lds(
          (const __attribute__((address_space(1))) unsigned int*)src,
          (__attribute__((address_space(3))) unsigned int*)(Lds + bufb + i * 4096 + (tid >> 6) * 1024),
          16, 0, 0);
    }
#pragma unroll
    for (int i = 0; i < 4; ++i) {
      int row = i * 32 + (tid >> 3);
      const unsigned short* src =
          Vt + ((size_t)(g * HD + row)) * SEQ + j * 64 + ((tid & 7) ^ (row & 7)) * 8;
      __builtin_amdgcn_global_load_lds(
          (const __attribute__((address_space(1))) unsigned int*)src,
          (__attribute__((address_space(3))) unsigned int*)(Lds + bufb + 16384 + i * 4096 + (tid >> 6) * 1024),
          16, 0, 0);
    }
  };

  bf16x8 qf[8];
  const unsigned short* qbase = Q + ((size_t)h * SEQ + Q0 + l31) * HD;
#pragma unroll
  for (int kk = 0; kk < 8; ++kk)
    qf[kk] = *reinterpret_cast<const bf16x8*>(qbase + kk * 16 + hi * 8);

  f32x16 ot[4] = {};
  float mrow = -1e30f, lsum = 0.f;

  const int kswz = l31 & 15;
  const int vswz = l31 & 7;

  int j = nextj(0, qb);
  int cur = 0;
  stage(0, j);
  asm volatile("s_waitcnt vmcnt(0)" ::: "memory");
  __builtin_amdgcn_sched_barrier(0);
  __builtin_amdgcn_s_barrier();
  __builtin_amdgcn_sched_barrier(0);

  while (true) {
    const int jn = (j < qb) ? nextj(j + 1, qb) : -1;
    if (jn >= 0) stage(cur ^ 32768, jn);

    const char* kb = Lds + cur;
    const char* vb = Lds + cur + 16384;
    const bool diag = (j == qb);
    const bool short_blk = diag && (half == 0);

    f32x16 st[2] = {};
    __builtin_amdgcn_s_setprio(1);
#pragma unroll
    for (int kk = 0; kk < 8; ++kk) {
      bf16x8 k0 = *reinterpret_cast<const bf16x8*>(
          kb + (size_t)l31 * 256 + (((2 * kk + hi) ^ kswz) * 16));
      st[0] = __builtin_amdgcn_mfma_f32_32x32x16_bf16(k0, qf[kk], st[0], 0, 0, 0);
      if (!short_blk) {
        bf16x8 k1 = *reinterpret_cast<const bf16x8*>(
            kb + (size_t)(32 + l31) * 256 + (((2 * kk + hi) ^ kswz) * 16));
        st[1] = __builtin_amdgcn_mfma_f32_32x32x16_bf16(k1, qf[kk], st[1], 0, 0, 0);
      }
    }
    __builtin_amdgcn_s_setprio(0);

    if (diag) {
      int qrel = half * 32 + l31;
#pragma unroll
      for (int kt = 0; kt < 2; ++kt)
#pragma unroll
        for (int r = 0; r < 16; ++r) {
          int krel = kt * 32 + (r & 3) + 8 * (r >> 2) + 4 * hi;
          if (krel > qrel) st[kt][r] = -1e30f;
        }
    }

    float t16[16];
#pragma unroll
    for (int r = 0; r < 16; ++r) t16[r] = fmaxf(st[0][r], st[1][r]);
#pragma unroll
    for (int sft = 8; sft >= 1; sft >>= 1)
#pragma unroll
      for (int r = 0; r < sft; ++r) t16[r] = fmaxf(t16[r], t16[r + sft]);
    float vm = xmax32(t16[0]);

    if (!__all(vm - mrow <= 8.0f)) {
      float nm = fmaxf(mrow, vm);
      float corr = __builtin_amdgcn_exp2f(mrow - nm);
      lsum *= corr;
#pragma unroll
      for (int dt = 0; dt < 4; ++dt)
#pragma unroll
        for (int r = 0; r < 16; ++r) ot[dt][r] *= corr;
      mrow = nm;
    }

    float s4[4] = {0.f, 0.f, 0.f, 0.f};
#pragma unroll
    for (int kt = 0; kt < 2; ++kt)
#pragma unroll
      for (int r = 0; r < 16; ++r) {
        float p = __builtin_amdgcn_exp2f(st[kt][r] - mrow);
        st[kt][r] = p;
        s4[r & 3] += p;
      }
    lsum += xadd32((s4[0] + s4[1]) + (s4[2] + s4[3]));

    bf16x8 pb[4];
#pragma unroll
    for (int s = 0; s < 4; ++s) {
      int kt = s >> 1, g0 = (s & 1) * 2, g1 = g0 + 1;
      unsigned int a0 = pk(st[kt][4 * g0 + 0], st[kt][4 * g0 + 1]);
      unsigned int a1 = pk(st[kt][4 * g0 + 2], st[kt][4 * g0 + 3]);
      unsigned int b0 = pk(st[kt][4 * g1 + 0], st[kt][4 * g1 + 1]);
      unsigned int b1 = pk(st[kt][4 * g1 + 2], st[kt][4 * g1 + 3]);
      pswap(a0, b0);
      pswap(a1, b1);
      union { unsigned int u[4]; bf16x8 v; } t;
      t.u[0] = a0; t.u[1] = a1; t.u[2] = b0; t.u[3] = b1;
      pb[s] = t.v;
    }

    const int smax = short_blk ? 2 : 4;
    __builtin_amdgcn_s_setprio(1);
#pragma unroll
    for (int dt = 0; dt < 4; ++dt) {
      const char* vrow = vb + (size_t)(dt * 32 + l31) * 128;
#pragma unroll
      for (int s = 0; s < 4; ++s)
        if (s < smax)
          ot[dt] = __builtin_amdgcn_mfma_f32_32x32x16_bf16(
              *reinterpret_cast<const bf16x8*>(vrow + (((2 * s + hi) ^ vswz) * 16)),
              pb[s], ot[dt], 0, 0, 0);
    }
    __builtin_amdgcn_s_setprio(0);

    if (jn < 0) break;
    asm volatile("s_waitcnt vmcnt(0)" ::: "memory");
    __builtin_amdgcn_sched_barrier(0);
    __builtin_amdgcn_s_barrier();
    __builtin_amdgcn_sched_barrier(0);
    j = jn;
    cur ^= 32768;
  }

  __syncthreads();
  char* W = Lds + wave * 8192;
  float inv = 1.0f / lsum;
  const int swz = (l31 & 7) << 4;
#pragma unroll
  for (int dt = 0; dt < 4; ++dt)
#pragma unroll
    for (int gg = 0; gg < 4; ++gg) {
      unsigned int u0 = pk(ot[dt][4 * gg + 0] * inv, ot[dt][4 * gg + 1] * inv);
      unsigned int u1 = pk(ot[dt][4 * gg + 2] * inv, ot[dt][4 * gg + 3] * inv);
      int off = (dt * 64 + gg * 16 + hi * 8) ^ swz;
      *reinterpret_cast<uint2*>(W + l31 * 256 + off) = make_uint2(u0, u1);
    }
#pragma unroll
  for (int i = 0; i < 8; ++i) {
    int row = lane >> 1;
    int t = (lane & 1) * 8 + i;
    bf16x8 vv = *reinterpret_cast<const bf16x8*>(
        W + row * 256 + ((t * 16) ^ ((row & 7) << 4)));
    *reinterpret_cast<bf16x8*>(&ctx[(size_t)(Q0 + row) * HIDDEN + h * HD + t * 8]) = vv;
  }
}

extern "C" void kernel_launch(void* const* d_in, const int* in_sizes, int n_in,
                              void* d_out, int out_size, void* d_ws, size_t ws_size,
                              hipStream_t stream) {
  const float* hidden  = (const float*)d_in[0];
  const float* w_qkv   = (const float*)d_in[1];
  const float* b_qkv   = (const float*)d_in[2];
  const float* w_dense = (const float*)d_in[3];
  const float* b_dense = (const float*)d_in[4];
  float* out = (float*)d_out;

  char* p = (char*)d_ws;
  unsigned short* hid_bf  = (unsigned short*)p; p += (size_t)SEQ * HIDDEN * 2;
  unsigned short* wqkv_bf = (unsigned short*)p; p += (size_t)QKV_OUT * HIDDEN * 2;
  unsigned short* wd_bf   = (unsigned short*)p; p += (size_t)HIDDEN * HIDDEN * 2;
  unsigned short* qkvb    = (unsigned short*)p; p += (size_t)SEQ * QKV_OUT * 2;
  unsigned short* Qb      = (unsigned short*)p; p += (size_t)NH * SEQ * HD * 2;
  unsigned short* Kb      = (unsigned short*)p; p += (size_t)NKV * SEQ * HD * 2;
  unsigned short* Vt      = (unsigned short*)p; p += (size_t)NKV * HD * SEQ * 2;
  float* ct               = (float*)p;          p += (size_t)SEQ * 64 * 4;
  float* st               = (float*)p;          p += (size_t)SEQ * 64 * 4;
  unsigned short* ctx = hid_bf;  // hidden_bf16 dead after QKV GEMM

  conv_bf16<<<(SEQ * HIDDEN) / 2048, 256, 0, stream>>>(hidden, hid_bf, SEQ * HIDDEN);
  conv_bf16<<<(QKV_OUT * HIDDEN) / 2048, 256, 0, stream>>>(w_qkv, wqkv_bf, QKV_OUT * HIDDEN);
  conv_bf16<<<(HIDDEN * HIDDEN) / 2048, 256, 0, stream>>>(w_dense, wd_bf, HIDDEN * HIDDEN);
  build_tab<<<(SEQ * 64) / 256, 256, 0, stream>>>(ct, st);

  // QKV: grid 8x24 = 192 tiles, XCD chunk 4x6. Output bf16.
  gemm8<256, 256, 2, 2, 4, 6, true>
      <<<dim3((SEQ / 256) * (QKV_OUT / 256)), 512, 0, stream>>>(
          hid_bf, wqkv_bf, b_qkv, qkvb, SEQ, QKV_OUT, HIDDEN);
  rope_split<<<5120 + 1024, 256, 0, stream>>>(qkvb, ct, st, Qb, Kb, Vt);
  attn32<<<dim3(NKV, SEQ / 32), 256, 0, stream>>>(Qb, Kb, Vt, ctx);
  // dense: grid 16x16 = 256 tiles, XCD chunk 8x4. Output fp32.
  gemm8<128, 256, 1, 2, 8, 4, false>
      <<<dim3((SEQ / 128) * (HIDDEN / 256)), 512, 0, stream>>>(
          ctx, wd_bf, b_dense, out, SEQ, HIDDEN, HIDDEN);
}